// Round 11
// baseline (439.439 us; speedup 1.0000x reference)
//
#include <hip/hip_runtime.h>
#include <hip/hip_fp16.h>

typedef _Float16 f16;
typedef _Float16 f16x4 __attribute__((ext_vector_type(4)));
typedef _Float16 f16x8 __attribute__((ext_vector_type(8)));
typedef float f32x4 __attribute__((ext_vector_type(4)));

#define DEV __device__ __forceinline__

// ---- problem constants ----
constexpr int BB    = 2;
constexpr int LL    = 4096;
constexpr int DM    = 1024;
constexpr int DIN   = 2048;
constexpr int DST   = 128;
constexpr int NH    = 32;
constexpr int HD    = 64;
constexpr int NC    = 64;                  // chunks per batch
constexpr int MROWS = BB * LL;             // 8192
constexpr int NPROJ = 2*DIN + 2*DST + NH;  // 4384 (W_in row stride)
constexpr int NZ    = 2*DIN + 2*DST;       // 4352 (z + xBC, GEMM1 N)
constexpr int CONVD = DIN + 2*DST;         // 2304
constexpr int DT_OFF = 2*DIN + 2*DST;      // 4352
constexpr int BOFF  = DIN;                 // 2048 (within NZ / CONVD)
constexpr int COFF  = DIN + DST;           // 2176

DEV float silu_f(float v) { return v / (1.f + __expf(-v)); }

// wave-uniform LDS dest; HW writes lane i at dst + i*16B. Per-lane global src.
DEV void gload_lds16(const f16* gsrc, f16* lds_dst) {
  __builtin_amdgcn_global_load_lds(
      (const __attribute__((address_space(1))) void*)gsrc,
      (__attribute__((address_space(3))) void*)lds_dst, 16, 0, 0);
}

// ---------------- fp32 -> fp16 convert ----------------
__global__ __launch_bounds__(256)
void tof16_kernel(const float* __restrict__ src, f16* __restrict__ dst, int n8) {
  int i = blockIdx.x * 256 + threadIdx.x;
  if (i >= n8) return;
  f32x4 a = *(const f32x4*)(src + (size_t)i*8);
  f32x4 b = *(const f32x4*)(src + (size_t)i*8 + 4);
  f16x8 o;
#pragma unroll
  for (int j = 0; j < 4; ++j) { o[j] = (f16)a[j]; o[4+j] = (f16)b[j]; }
  *(f16x8*)(dst + (size_t)i*8) = o;
}

// ------------- transpose fp32[K rows][srcLd cols] -> fp16[N][K] -------------
__global__ __launch_bounds__(256)
void transpose_f32_to_f16(const float* __restrict__ src, f16* __restrict__ dst,
                          int K, int N, int srcLd) {
  __shared__ float tbuf[32][33];
  int n0 = blockIdx.x * 32, k0 = blockIdx.y * 32;
  int tx = threadIdx.x & 31, ty = threadIdx.x >> 5;  // 32 x 8
  for (int i = ty; i < 32; i += 8)
    tbuf[i][tx] = src[(size_t)(k0 + i)*srcLd + n0 + tx];
  __syncthreads();
  for (int i = ty; i < 32; i += 8)
    dst[(size_t)(n0 + i)*K + (k0 + tx)] = (f16)tbuf[tx][i];
}

// ------- 8-phase-style MFMA GEMM (m201 port): C[M][ldc] = A[M][K]*Bt[N][K]^T -------
// BM=256,BN=128,BK=64; 8 waves (4Mx2N), wave tile 64x64. 3 LDS buffers (144KB).
// Per K-tile: 2 phases x {8 ds_read_b128 | 3 global_load_lds | barrier |
// lgkmcnt(0)+sched_barrier | setprio(1) 16 MFMA setprio(0) | barrier}.
// vmcnt(6) only at tile boundary (T4, never 0 mid-loop). st_16x32 swizzle
// (byte ^= ((byte>>9)&1)<<5) applied both-sides: pre-swizzled global SOURCE
// (linear gload dest) + swizzled ds_read address (rule 21, m201 pairing).
template<bool C16>
__global__ __launch_bounds__(512, 1)
void gemm_8p(const f16* __restrict__ A, const f16* __restrict__ Bt,
             void* __restrict__ Cp, int M, int N, int K, int ldc) {
  constexpr int BM = 256, BN = 128, BK = 64;
  constexpr int AF16 = BM*BK;       // 16384 f16 per buffer
  constexpr int BF16 = BN*BK;       // 8192
  constexpr int BUF  = AF16 + BF16; // 24576 f16 = 48 KB
  __shared__ f16 smem[3*BUF];       // 147456 B
  const int nbn = N / BN;
  const int bm = blockIdx.x / nbn, bn = blockIdx.x % nbn;
  const int tid = threadIdx.x;
  const int wave = tid >> 6, lane = tid & 63;
  const int lrow = lane & 15, kgrp = lane >> 4;
  const int wm = wave >> 1, wn = wave & 1;  // 4M x 2N
  const int nt = K / BK;

  // staging: A = 4 loads/thread, B = 2 (16B chunks). Global src pre-swizzled.
  const f16* aSrc[4]; const f16* bSrc[2];
  int dA[4], dB[2];
#pragma unroll
  for (int i = 0; i < 4; ++i) {
    int Lb = ((i*8 + wave)*64 + lane) * 16;
    int sw = Lb ^ (((Lb >> 9) & 1) << 5);
    int row = sw >> 7, colf = (sw & 127) >> 1;
    aSrc[i] = A + (size_t)(bm*BM + row)*K + colf;
    dA[i] = (i*8 + wave) * 512;          // wave-uniform LDS dst (f16 units)
  }
#pragma unroll
  for (int i = 0; i < 2; ++i) {
    int Lb = ((i*8 + wave)*64 + lane) * 16;
    int sw = Lb ^ (((Lb >> 9) & 1) << 5);
    int row = sw >> 7, colf = (sw & 127) >> 1;
    bSrc[i] = Bt + (size_t)(bn*BN + row)*K + colf;
    dB[i] = (i*8 + wave) * 512;
  }
  // reader fragment offsets (swizzled), f16 units
  int aIdx[4][2], bIdx[4][2];
#pragma unroll
  for (int m = 0; m < 4; ++m)
#pragma unroll
    for (int kk = 0; kk < 2; ++kk) {
      int r = wm*64 + m*16 + lrow;
      int off = r*128 + kk*64 + kgrp*16;
      aIdx[m][kk] = (off ^ (((off >> 9) & 1) << 5)) >> 1;
      r = wn*64 + m*16 + lrow;
      off = r*128 + kk*64 + kgrp*16;
      bIdx[m][kk] = (off ^ (((off >> 9) & 1) << 5)) >> 1;
    }

  f32x4 acc[4][4] = {};

  auto STAGE = [&](int buf, int t, int s) {
    f16* Ab = smem + buf*BUF;
    f16* Bb = Ab + AF16;
    if (s == 0) {
      gload_lds16(aSrc[0] + (size_t)t*BK, Ab + dA[0]);
      gload_lds16(aSrc[1] + (size_t)t*BK, Ab + dA[1]);
      gload_lds16(bSrc[0] + (size_t)t*BK, Bb + dB[0]);
    } else {
      gload_lds16(aSrc[2] + (size_t)t*BK, Ab + dA[2]);
      gload_lds16(aSrc[3] + (size_t)t*BK, Ab + dA[3]);
      gload_lds16(bSrc[1] + (size_t)t*BK, Bb + dB[1]);
    }
  };

  // prologue: tiles 0 and 1 in flight; wait tile 0 (6 newest stay in flight)
  STAGE(0, 0, 0); STAGE(0, 0, 1);
  if (nt > 1) { STAGE(1, 1, 0); STAGE(1, 1, 1);
    asm volatile("s_waitcnt vmcnt(6)" ::: "memory");
  } else {
    asm volatile("s_waitcnt vmcnt(0)" ::: "memory");
  }
  __builtin_amdgcn_s_barrier();
  __builtin_amdgcn_sched_barrier(0);

  for (int t = 0; t < nt; ++t) {
    const int cur = t % 3;
    const f16* Ab = smem + cur*BUF;
    const f16* Bb = Ab + AF16;
    f16x8 af[4], bf[4];
    // ---------- phase 0 (kk=0) ----------
#pragma unroll
    for (int m = 0; m < 4; ++m) af[m] = *(const f16x8*)(Ab + aIdx[m][0]);
#pragma unroll
    for (int n = 0; n < 4; ++n) bf[n] = *(const f16x8*)(Bb + bIdx[n][0]);
    if (t + 2 < nt) STAGE((t + 2) % 3, t + 2, 0);
    __builtin_amdgcn_s_barrier();
    asm volatile("s_waitcnt lgkmcnt(0)" ::: "memory");
    __builtin_amdgcn_sched_barrier(0);
    __builtin_amdgcn_s_setprio(1);
#pragma unroll
    for (int m = 0; m < 4; ++m)
#pragma unroll
      for (int n = 0; n < 4; ++n)
        acc[m][n] = __builtin_amdgcn_mfma_f32_16x16x32_f16(af[m], bf[n], acc[m][n], 0, 0, 0);
    __builtin_amdgcn_s_setprio(0);
    __builtin_amdgcn_s_barrier();
    __builtin_amdgcn_sched_barrier(0);
    // ---------- phase 1 (kk=1) ----------
#pragma unroll
    for (int m = 0; m < 4; ++m) af[m] = *(const f16x8*)(Ab + aIdx[m][1]);
#pragma unroll
    for (int n = 0; n < 4; ++n) bf[n] = *(const f16x8*)(Bb + bIdx[n][1]);
    if (t + 2 < nt) STAGE((t + 2) % 3, t + 2, 1);
    if (t + 1 < nt) {
      if (t + 2 < nt) asm volatile("s_waitcnt vmcnt(6)" ::: "memory");
      else            asm volatile("s_waitcnt vmcnt(0)" ::: "memory");
    }
    __builtin_amdgcn_s_barrier();
    asm volatile("s_waitcnt lgkmcnt(0)" ::: "memory");
    __builtin_amdgcn_sched_barrier(0);
    __builtin_amdgcn_s_setprio(1);
#pragma unroll
    for (int m = 0; m < 4; ++m)
#pragma unroll
      for (int n = 0; n < 4; ++n)
        acc[m][n] = __builtin_amdgcn_mfma_f32_16x16x32_f16(af[m], bf[n], acc[m][n], 0, 0, 0);
    __builtin_amdgcn_s_setprio(0);
    __builtin_amdgcn_s_barrier();
    __builtin_amdgcn_sched_barrier(0);
  }

  int crow0 = bm*BM + wm*64, ccol0 = bn*BN + wn*64;
#pragma unroll
  for (int m = 0; m < 4; ++m)
#pragma unroll
    for (int n = 0; n < 4; ++n) {
      int r0 = crow0 + m*16 + (lane >> 4)*4;
      int c0 = ccol0 + n*16 + (lane & 15);
#pragma unroll
      for (int r = 0; r < 4; ++r) {
        if constexpr (C16) {
          f16* C = (f16*)Cp;
          C[(size_t)(r0 + r)*ldc + c0] = (f16)acc[m][n][r];
        } else {
          float* C = (float*)Cp;
          C[(size_t)(r0 + r)*ldc + c0] = acc[m][n][r];
        }
      }
    }
}

// ---------------- exact fp32 dt: softplus(x @ Win[:,DT_OFF:] + bias) ----------------
__global__ __launch_bounds__(256)
void dt_kernel(const float* __restrict__ x, const float* __restrict__ Win,
               const float* __restrict__ dt_bias, float* __restrict__ dt) {
  __shared__ float xs[64][132];
  __shared__ float ws[128][32];
  int r0 = blockIdx.x * 64;
  int t = threadIdx.x;
  int r = t >> 2, c0 = (t & 3) * 8;
  float acc[8] = {};
  for (int kt = 0; kt < 1024; kt += 128) {
    __syncthreads();
#pragma unroll
    for (int i = 0; i < 8; ++i) {
      int idx4 = t + i*256;
      int rr = idx4 >> 5, c4 = (idx4 & 31) * 4;
      *(f32x4*)&xs[rr][c4] = *(const f32x4*)(x + (size_t)(r0 + rr)*1024 + kt + c4);
    }
#pragma unroll
    for (int i = 0; i < 4; ++i) {
      int idx4 = t + i*256;
      int rr = idx4 >> 3, c4 = (idx4 & 7) * 4;
      *(f32x4*)&ws[rr][c4] = *(const f32x4*)(Win + (size_t)(kt + rr)*NPROJ + DT_OFF + c4);
    }
    __syncthreads();
#pragma unroll 8
    for (int k = 0; k < 128; ++k) {
      float xv = xs[r][k];
      f32x4 w0 = *(const f32x4*)&ws[k][c0];
      f32x4 w1 = *(const f32x4*)&ws[k][c0 + 4];
#pragma unroll
      for (int j = 0; j < 4; ++j) { acc[j] += xv * w0[j]; acc[4+j] += xv * w1[j]; }
    }
  }
#pragma unroll
  for (int j = 0; j < 8; ++j) {
    float v = acc[j] + dt_bias[c0 + j];
    float sp = (v > 20.f) ? v : log1pf(__expf(v));
    dt[(size_t)(r0 + r)*NH + c0 + j] = sp;
  }
}

// ---------------- causal depthwise conv (k=4) + bias + silu -> fp16 ----------------
__global__ __launch_bounds__(256)
void conv_kernel(const f16* __restrict__ zxh, const float* __restrict__ cw,
                 const float* __restrict__ cb, f16* __restrict__ out) {
  int i = blockIdx.x * 256 + threadIdx.x;      // MROWS * 288
  int row = i / (CONVD/8);
  int c8  = (i - row*(CONVD/8)) * 8;
  int lb = row & (LL - 1);
  f32x4 a0 = *(const f32x4*)(cb + c8);
  f32x4 a1 = *(const f32x4*)(cb + c8 + 4);
#pragma unroll
  for (int j = 0; j < 4; ++j) {
    int lsrc = lb - 3 + j;
    if (lsrc >= 0) {
      f16x8 v = *(const f16x8*)(zxh + (size_t)(row - 3 + j)*NZ + BOFF + c8);
      f32x4 w0 = *(const f32x4*)(cw + j*CONVD + c8);
      f32x4 w1 = *(const f32x4*)(cw + j*CONVD + c8 + 4);
#pragma unroll
      for (int jj = 0; jj < 4; ++jj) {
        a0[jj] += (float)v[jj]   * w0[jj];
        a1[jj] += (float)v[4+jj] * w1[jj];
      }
    }
  }
  f16x8 o;
#pragma unroll
  for (int jj = 0; jj < 4; ++jj) {
    o[jj]   = (f16)silu_f(a0[jj]);
    o[4+jj] = (f16)silu_f(a1[jj]);
  }
  *(f16x8*)(out + (size_t)row*CONVD + c8) = o;
}

// ---------------- per-chunk inclusive cumsum of a = A[h]*dt ----------------
__global__ __launch_bounds__(256)
void acum_kernel(const float* __restrict__ dt, const float* __restrict__ A_log,
                 float* __restrict__ Acum) {
  int bc = blockIdx.x;                  // b*NC + c
  int wave = threadIdx.x >> 6, lane = threadIdx.x & 63;
  int row = bc*64 + lane;
  for (int hh = 0; hh < 8; ++hh) {
    int h = wave*8 + hh;
    float A = -__expf(A_log[h]);
    float v = A * dt[(size_t)row*NH + h];
#pragma unroll
    for (int off = 1; off < 64; off <<= 1) {
      float u = __shfl_up(v, off);
      if (lane >= off) v += u;
    }
    Acum[((size_t)bc*NH + h)*64 + lane] = v;
  }
}

// ---------------- G[bc][l][s] = sum_n C[l,n] * B[s,n] (head-independent, f16 out) ----------------
__global__ __launch_bounds__(256)
void gbuf_kernel(const f16* __restrict__ xbc, f16* __restrict__ G) {
  __shared__ float Cs[64][128];
  __shared__ float Bsm[64][128];
  int bc = blockIdx.x;
  int row0 = bc * 64;
  int t = threadIdx.x;
#pragma unroll
  for (int i = 0; i < 4; ++i) {
    int idx = t + i*256;                 // 0..1023 -> 64 rows x 16 col-groups
    int r = idx >> 4, c8 = (idx & 15) * 8;
    f16x8 cv = *(const f16x8*)(xbc + (size_t)(row0 + r)*CONVD + COFF + c8);
    f16x8 bv = *(const f16x8*)(xbc + (size_t)(row0 + r)*CONVD + BOFF + c8);
    f32x4 c0v = {(float)cv[0], (float)cv[1], (float)cv[2], (float)cv[3]};
    f32x4 c1v = {(float)cv[4], (float)cv[5], (float)cv[6], (float)cv[7]};
    f32x4 b0v = {(float)bv[0], (float)bv[1], (float)bv[2], (float)bv[3]};
    f32x4 b1v = {(float)bv[4], (float)bv[5], (float)bv[6], (float)bv[7]};
    *(f32x4*)&Cs[r][c8]      = c0v;  *(f32x4*)&Cs[r][c8 + 4]  = c1v;
    *(f32x4*)&Bsm[r][c8]     = b0v;  *(f32x4*)&Bsm[r][c8 + 4] = b1v;
  }
  __syncthreads();
  int l0 = (t >> 4)*4, s0 = (t & 15)*4;
  float acc[4][4] = {};
  for (int n4 = 0; n4 < 128; n4 += 4) {
    f32x4 cv[4], bv[4];
#pragma unroll
    for (int i = 0; i < 4; ++i) cv[i] = *(const f32x4*)&Cs[l0 + i][n4];
#pragma unroll
    for (int j = 0; j < 4; ++j) bv[j] = *(const f32x4*)&Bsm[s0 + j][n4];
#pragma unroll
    for (int i = 0; i < 4; ++i)
#pragma unroll
      for (int j = 0; j < 4; ++j)
        acc[i][j] += cv[i][0]*bv[j][0] + cv[i][1]*bv[j][1] + cv[i][2]*bv[j][2] + cv[i][3]*bv[j][3];
  }
#pragma unroll
  for (int i = 0; i < 4; ++i) {
    f16x4 v = {(f16)acc[i][0], (f16)acc[i][1], (f16)acc[i][2], (f16)acc[i][3]};
    *(f16x4*)(G + ((size_t)bc*64 + l0 + i)*64 + s0) = v;
  }
}

// ------- per (b,c,h): Y_diag + chunk states, MFMA (fused) -------
__global__ __launch_bounds__(256)
void ssd_a_kernel(const f16* __restrict__ xbc, const float* __restrict__ dtb,
                  const f16* __restrict__ Gg, const float* __restrict__ Acum,
                  f16* __restrict__ Ybuf, f16* __restrict__ states) {
  __shared__ union {
    struct { f16 XdT[64][72]; f16 Gt[64][72]; f16 BT[128][72]; } s;  // 36 KB
    float Yl[64][68];    // ydiag retile
    float Sl[64][132];   // states retile
  } u;
  __shared__ float ac[64], dts[64];
  int bc = blockIdx.x >> 5, h = blockIdx.x & 31;
  int row0 = bc*64, t = threadIdx.x;
  if (t < 64) {
    ac[t]  = Acum[((size_t)bc*NH + h)*64 + t];
    dts[t] = dtb[(size_t)(row0 + t)*NH + h];
  }
  __syncthreads();
  float ac63 = ac[63];
#pragma unroll
  for (int i = 0; i < 2; ++i) {
    int idx = t + i*256; int l = idx >> 3, p8 = (idx & 7)*8;
    f16x8 v = *(const f16x8*)(xbc + (size_t)(row0 + l)*CONVD + h*HD + p8);
    float d = dts[l];
#pragma unroll
    for (int j = 0; j < 8; ++j) u.s.XdT[p8 + j][l] = (f16)((float)v[j]*d);
  }
#pragma unroll
  for (int i = 0; i < 4; ++i) {
    int idx = t + i*256; int l = idx >> 4, n8 = (idx & 15)*8;
    f16x8 v = *(const f16x8*)(xbc + (size_t)(row0 + l)*CONVD + BOFF + n8);
    float dl = __expf(ac63 - ac[l]);
#pragma unroll
    for (int j = 0; j < 8; ++j) u.s.BT[n8 + j][l] = (f16)((float)v[j]*dl);
  }
#pragma unroll
  for (int i = 0; i < 2; ++i) {
    int idx = t + i*256; int l = idx >> 3, s8 = (idx & 7)*8;
    f16x8 g = *(const f16x8*)(Gg + (size_t)bc*4096 + l*64 + s8);
    float al = ac[l];
    f16x8 o;
#pragma unroll
    for (int j = 0; j < 8; ++j) {
      int s = s8 + j;
      o[j] = (l >= s) ? (f16)((float)g[j] * __expf(al - ac[s])) : (f16)0.f;
    }
    *(f16x8*)&u.s.Gt[l][s8] = o;
  }
  __syncthreads();
  int wave = t >> 6, lane = t & 63;
  int lrow = lane & 15, kgrp = lane >> 4;
  f32x4 yacc[4] = {};
  f32x4 sacc[8] = {};
#pragma unroll
  for (int kk = 0; kk < 64; kk += 32) {
    f16x8 afy = *(const f16x8*)&u.s.Gt[wave*16 + lrow][kk + kgrp*8];
    f16x8 afs = *(const f16x8*)&u.s.XdT[wave*16 + lrow][kk + kgrp*8];
#pragma unroll
    for (int n = 0; n < 4; ++n) {
      f16x8 bf = *(const f16x8*)&u.s.XdT[n*16 + lrow][kk + kgrp*8];
      yacc[n] = __builtin_amdgcn_mfma_f32_16x16x32_f16(afy, bf, yacc[n], 0, 0, 0);
    }
#pragma unroll
    for (int n = 0; n < 8; ++n) {
      f16x8 bf = *(const f16x8*)&u.s.BT[n*16 + lrow][kk + kgrp*8];
      sacc[n] = __builtin_amdgcn_mfma_f32_16x16x32_f16(afs, bf, sacc[n], 0, 0, 0);
    }
  }
  __syncthreads();
#pragma unroll
  for (int n = 0; n < 4; ++n)
#pragma unroll
    for (int r = 0; r < 4; ++r)
      u.Yl[wave*16 + kgrp*4 + r][n*16 + lrow] = yacc[n][r];
  __syncthreads();
#pragma unroll
  for (int i = 0; i < 2; ++i) {
    int idx = t + i*256; int l = idx >> 3, p8 = (idx & 7)*8;
    f16x8 o;
#pragma unroll
    for (int j = 0; j < 8; ++j) o[j] = (f16)u.Yl[l][p8 + j];
    *(f16x8*)(Ybuf + (size_t)(row0 + l)*DIN + h*HD + p8) = o;
  }
  __syncthreads();
#pragma unroll
  for (int n = 0; n < 8; ++n)
#pragma unroll
    for (int r = 0; r < 4; ++r)
      u.Sl[wave*16 + kgrp*4 + r][n*16 + lrow] = sacc[n][r];
  __syncthreads();
  size_t sb = ((size_t)bc*NH + h)*8192;
#pragma unroll
  for (int i = 0; i < 4; ++i) {
    int idx = t + i*256; int p = idx >> 4, n8 = (idx & 15)*8;
    f16x8 o;
#pragma unroll
    for (int j = 0; j < 8; ++j) o[j] = (f16)u.Sl[p][n8 + j];
    *(f16x8*)(states + sb + (size_t)p*128 + n8) = o;
  }
}

// ---------------- inter-chunk scan (in place, fp16 storage, fp32 carry) ----------------
__global__ __launch_bounds__(256)
void scan_kernel(f16* __restrict__ states, const float* __restrict__ Acum) {
  int bid = blockIdx.x;
  int bh = bid >> 3, pgrp = bid & 7;
  int b = bh >> 5, h = bh & 31;
  int t = threadIdx.x;
  int p = pgrp*8 + (t >> 5), n4 = (t & 31) * 4;
  size_t off = (size_t)p*128 + n4;
  f32x4 carry = {0.f, 0.f, 0.f, 0.f};
  for (int c = 0; c < NC; ++c) {
    size_t base = ((size_t)(b*NC + c)*NH + h)*8192;
    f16x4 cv = *(f16x4*)(states + base + off);
    f16x4 st;
#pragma unroll
    for (int j = 0; j < 4; ++j) st[j] = (f16)carry[j];
    *(f16x4*)(states + base + off) = st;
    float tc = __expf(Acum[((size_t)(b*NC + c)*NH + h)*64 + 63]);
#pragma unroll
    for (int j = 0; j < 4; ++j) carry[j] = carry[j]*tc + (float)cv[j];
  }
}

// ------- Y_off (MFMA) + D-skip + SiLU(z) gating (in-place, fp16 Ybuf) -------
__global__ __launch_bounds__(256)
void yoff_kernel(const f16* __restrict__ xbc, const f16* __restrict__ zxh,
                 const f16* __restrict__ states, const float* __restrict__ Acum,
                 const float* __restrict__ Dp, f16* __restrict__ Ybuf) {
  __shared__ union {
    struct { f16 Ch[64][136]; f16 Sin[64][136]; } s;  // 34 KB
    float Yl[64][68];
  } u;
  __shared__ float eac[64];
  int bc = blockIdx.x >> 5, h = blockIdx.x & 31;
  int row0 = bc*64, t = threadIdx.x;
  if (t < 64) eac[t] = __expf(Acum[((size_t)bc*NH + h)*64 + t]);
  size_t sb = ((size_t)bc*NH + h)*8192;
#pragma unroll
  for (int i = 0; i < 4; ++i) {
    int idx = t + i*256; int r = idx >> 4, c8 = (idx & 15)*8;
    *(f16x8*)&u.s.Ch[r][c8]  = *(const f16x8*)(xbc + (size_t)(row0 + r)*CONVD + COFF + c8);
    *(f16x8*)&u.s.Sin[r][c8] = *(const f16x8*)(states + sb + (size_t)r*128 + c8);
  }
  __syncthreads();
  int wave = t >> 6, lane = t & 63;
  int lrow = lane & 15, kgrp = lane >> 4;
  f32x4 acc[4] = {};
#pragma unroll
  for (int kk = 0; kk < 128; kk += 32) {
    f16x8 af = *(const f16x8*)&u.s.Ch[wave*16 + lrow][kk + kgrp*8];
#pragma unroll
    for (int n = 0; n < 4; ++n) {
      f16x8 bf = *(const f16x8*)&u.s.Sin[n*16 + lrow][kk + kgrp*8];
      acc[n] = __builtin_amdgcn_mfma_f32_16x16x32_f16(af, bf, acc[n], 0, 0, 0);
    }
  }
  __syncthreads();
#pragma unroll
  for (int n = 0; n < 4; ++n)
#pragma unroll
    for (int r = 0; r < 4; ++r)
      u.Yl[wave*16 + kgrp*4 + r][n*16 + lrow] = acc[n][r];
  __syncthreads();
  float Dh = Dp[h];
#pragma unroll
  for (int i = 0; i < 2; ++i) {
    int idx = t + i*256; int l = idx >> 3, p8 = (idx & 7)*8;
    int row = row0 + l;
    f16x8 yd = *(const f16x8*)(Ybuf + (size_t)row*DIN + h*HD + p8);
    f16x8 zh = *(const f16x8*)(zxh + (size_t)row*NZ + h*HD + p8);
    f16x8 xs = *(const f16x8*)(xbc + (size_t)row*CONVD + h*HD + p8);
    float e = eac[l];
    f16x8 o;
#pragma unroll
    for (int j = 0; j < 8; ++j) {
      float yv = (float)yd[j] + e*u.Yl[l][p8 + j] + (float)xs[j]*Dh;
      o[j] = (f16)(yv * silu_f((float)zh[j]));
    }
    *(f16x8*)(Ybuf + (size_t)row*DIN + h*HD + p8) = o;
  }
}

// ---------------- RMSNorm + fp16 convert ----------------
__global__ __launch_bounds__(256)
void rms_kernel(const f16* __restrict__ yg, const float* __restrict__ nw,
                f16* __restrict__ yh) {
  __shared__ float red[4];
  int row = blockIdx.x, t = threadIdx.x;
  f16x8 v = *(const f16x8*)(yg + (size_t)row*DIN + t*8);
  float f[8];
  float ss = 0.f;
#pragma unroll
  for (int j = 0; j < 8; ++j) { f[j] = (float)v[j]; ss += f[j]*f[j]; }
#pragma unroll
  for (int off = 32; off > 0; off >>= 1) ss += __shfl_down(ss, off);
  if ((t & 63) == 0) red[t >> 6] = ss;
  __syncthreads();
  float tot = red[0] + red[1] + red[2] + red[3];
  float sc = rsqrtf(tot * (1.f/2048.f) + 1e-5f);
  f32x4 w0 = *(const f32x4*)(nw + t*8);
  f32x4 w1 = *(const f32x4*)(nw + t*8 + 4);
  f16x8 o;
#pragma unroll
  for (int j = 0; j < 4; ++j) {
    o[j]   = (f16)(f[j]   * sc * w0[j]);
    o[4+j] = (f16)(f[4+j] * sc * w1[j]);
  }
  *(f16x8*)(yh + (size_t)row*DIN + t*8) = o;
}

// ---------------- host launcher ----------------
extern "C" void kernel_launch(void* const* d_in, const int* in_sizes, int n_in,
                              void* d_out, int out_size, void* d_ws, size_t ws_size,
                              hipStream_t stream) {
  const float* x       = (const float*)d_in[0];
  const float* W_in    = (const float*)d_in[1];
  const float* conv_w  = (const float*)d_in[2];
  const float* conv_b  = (const float*)d_in[3];
  const float* dt_bias = (const float*)d_in[4];
  const float* A_log   = (const float*)d_in[5];
  const float* Dp      = (const float*)d_in[6];
  const float* norm_w  = (const float*)d_in[7];
  const float* W_out   = (const float*)d_in[8];

  constexpr size_t WS_NEED = 213909504;
  if (ws_size < WS_NEED) return;  // clean fail instead of OOB crash

  char* w = (char*)d_ws;
  f16*   states = (f16*)(w + 0);
  f16*   winT   = (f16*)(w + 0);
  f16*   yh     = (f16*)(w + 0);
  f16*   xh     = (f16*)(w + 33554432);
  f16*   woutT  = (f16*)(w + 33554432);
  f16*   zxh    = (f16*)(w + 67108864);
  f16*   xbcc   = (f16*)(w + 138412032);
  f16*   Ybuf   = (f16*)(w + 176160768);
  float* dtb    = (float*)(w + 209715200);
  float* Acum   = (float*)(w + 210763776);
  f16*   Gg     = (f16*)(w + 211812352);

  tof16_kernel<<<4096, 256, 0, stream>>>(x, xh, MROWS*DM/8);
  transpose_f32_to_f16<<<dim3(NZ/32, DM/32), 256, 0, stream>>>(W_in, winT, DM, NZ, NPROJ);
  gemm_8p<true><<<(MROWS/256)*(NZ/128), 512, 0, stream>>>(xh, winT, zxh, MROWS, NZ, DM, NZ);
  dt_kernel<<<MROWS/64, 256, 0, stream>>>(x, W_in, dt_bias, dtb);
  conv_kernel<<<MROWS*(CONVD/8)/256, 256, 0, stream>>>(zxh, conv_w, conv_b, xbcc);
  acum_kernel<<<BB*NC, 256, 0, stream>>>(dtb, A_log, Acum);
  gbuf_kernel<<<BB*NC, 256, 0, stream>>>(xbcc, Gg);
  ssd_a_kernel<<<BB*NC*NH, 256, 0, stream>>>(xbcc, dtb, Gg, Acum, Ybuf, states);
  scan_kernel<<<BB*NH*8, 256, 0, stream>>>(states, Acum);
  yoff_kernel<<<BB*NC*NH, 256, 0, stream>>>(xbcc, zxh, states, Acum, Dp, Ybuf);
  transpose_f32_to_f16<<<dim3(DM/32, DIN/32), 256, 0, stream>>>(W_out, woutT, DIN, DM, DM);
  rms_kernel<<<MROWS, 256, 0, stream>>>(Ybuf, norm_w, yh);
  gemm_8p<false><<<(MROWS/256)*(DM/128), 512, 0, stream>>>(yh, woutT, d_out, MROWS, DM, DIN, DM);
}

// Round 13
// 434.856 us; speedup vs baseline: 1.0105x; 1.0105x over previous
//
#include <hip/hip_runtime.h>
#include <hip/hip_fp16.h>

typedef _Float16 f16;
typedef _Float16 f16x4 __attribute__((ext_vector_type(4)));
typedef _Float16 f16x8 __attribute__((ext_vector_type(8)));
typedef float f32x4 __attribute__((ext_vector_type(4)));

#define DEV __device__ __forceinline__

// ---- problem constants ----
constexpr int BB    = 2;
constexpr int LL    = 4096;
constexpr int DM    = 1024;
constexpr int DIN   = 2048;
constexpr int DST   = 128;
constexpr int NH    = 32;
constexpr int HD    = 64;
constexpr int NC    = 64;                  // chunks per batch
constexpr int MROWS = BB * LL;             // 8192
constexpr int NPROJ = 2*DIN + 2*DST + NH;  // 4384 (W_in row stride)
constexpr int NZ    = 2*DIN + 2*DST;       // 4352 (z + xBC, GEMM1 N)
constexpr int CONVD = DIN + 2*DST;         // 2304
constexpr int DT_OFF = 2*DIN + 2*DST;      // 4352
constexpr int BOFF  = DIN;                 // 2048 (within NZ / CONVD)
constexpr int COFF  = DIN + DST;           // 2176

DEV float silu_f(float v) { return v / (1.f + __expf(-v)); }

// wave-uniform LDS dest; HW writes lane i at dst + i*16B. Per-lane global src.
DEV void gload_lds16(const f16* gsrc, f16* lds_dst) {
  __builtin_amdgcn_global_load_lds(
      (const __attribute__((address_space(1))) void*)gsrc,
      (__attribute__((address_space(3))) void*)lds_dst, 16, 0, 0);
}

// ---------------- fp32 -> fp16 convert ----------------
__global__ __launch_bounds__(256)
void tof16_kernel(const float* __restrict__ src, f16* __restrict__ dst, int n8) {
  int i = blockIdx.x * 256 + threadIdx.x;
  if (i >= n8) return;
  f32x4 a = *(const f32x4*)(src + (size_t)i*8);
  f32x4 b = *(const f32x4*)(src + (size_t)i*8 + 4);
  f16x8 o;
#pragma unroll
  for (int j = 0; j < 4; ++j) { o[j] = (f16)a[j]; o[4+j] = (f16)b[j]; }
  *(f16x8*)(dst + (size_t)i*8) = o;
}

// ------------- transpose fp32[K rows][srcLd cols] -> fp16[N][K] -------------
__global__ __launch_bounds__(256)
void transpose_f32_to_f16(const float* __restrict__ src, f16* __restrict__ dst,
                          int K, int N, int srcLd) {
  __shared__ float tbuf[32][33];
  int n0 = blockIdx.x * 32, k0 = blockIdx.y * 32;
  int tx = threadIdx.x & 31, ty = threadIdx.x >> 5;  // 32 x 8
  for (int i = ty; i < 32; i += 8)
    tbuf[i][tx] = src[(size_t)(k0 + i)*srcLd + n0 + tx];
  __syncthreads();
  for (int i = ty; i < 32; i += 8)
    dst[(size_t)(n0 + i)*K + (k0 + tx)] = (f16)tbuf[tx][i];
}

// ------- pipelined MFMA GEMM (R10 proven): C[M][ldc] = A[M][K] * Bt[N][K]^T -------
// BK=32, 3-buffer rotation, stage t+2 ahead, counted vmcnt (never 0 mid-loop).
// LDS <= 72KB keeps 2 blocks/CU (R8 lesson). NOTE (R10/R11): SQ_LDS_BANK_CONFLICT
// is invariant to read layout here -> conflicts come from gload_lds DMA writes;
// read-side swizzles are moot. This structure's plateau: ~113us / 28% MfmaUtil.
template<int BM, int BN, int WM_, int WN_, bool C16>
__global__ __launch_bounds__(WM_*WN_*64, 2)
void gemm_t(const f16* __restrict__ A, const f16* __restrict__ Bt,
            void* __restrict__ Cp, int M, int N, int K, int ldc) {
  constexpr int THREADS = WM_*WN_*64;
  constexpr int WTM = BM/WM_, WTN = BN/WN_;
  constexpr int FM = WTM/16, FN = WTN/16;
  constexpr int LA = BM*4/THREADS, LB = BN*4/THREADS;  // 16B-chunk loads/thread
  constexpr int L = LA + LB;
  __shared__ f16 As[3][BM*32];
  __shared__ f16 Bs[3][BN*32];
  const int nbn = N / BN;
  const int bm = blockIdx.x / nbn, bn = blockIdx.x % nbn;
  const int tid = threadIdx.x;
  const int wave = tid >> 6, lane = tid & 63;
  const int lrow = lane & 15, kgrp = lane >> 4;
  const int wm = wave / WN_, wn = wave % WN_;
  const int nt = K >> 5;
  const int bcol8 = (kgrp ^ ((lrow ^ (lrow >> 2)) & 3)) * 8;

  const f16* aptr[LA];
  const f16* bptr[LB];
#pragma unroll
  for (int i = 0; i < LA; ++i) {
    int s = tid + i*THREADS, row = s >> 2;
    int g = (s & 3) ^ ((row ^ (row >> 2)) & 3);
    aptr[i] = A + (size_t)(bm*BM + row)*K + g*8;
  }
#pragma unroll
  for (int i = 0; i < LB; ++i) {
    int s = tid + i*THREADS, row = s >> 2;
    int g = (s & 3) ^ ((row ^ (row >> 2)) & 3);
    bptr[i] = Bt + (size_t)(bn*BN + row)*K + g*8;
  }

  f32x4 acc[FM][FN] = {};

  auto STAGE = [&](int buf, int t) {
#pragma unroll
    for (int i = 0; i < LA; ++i)
      gload_lds16(aptr[i] + (size_t)t*32, As[buf] + (wave*64 + i*THREADS)*8);
#pragma unroll
    for (int i = 0; i < LB; ++i)
      gload_lds16(bptr[i] + (size_t)t*32, Bs[buf] + (wave*64 + i*THREADS)*8);
  };
  auto WAITL = [&]() {
    if constexpr (L == 2)      asm volatile("s_waitcnt vmcnt(2)" ::: "memory");
    else if constexpr (L == 3) asm volatile("s_waitcnt vmcnt(3)" ::: "memory");
    else if constexpr (L == 4) asm volatile("s_waitcnt vmcnt(4)" ::: "memory");
    else if constexpr (L == 6) asm volatile("s_waitcnt vmcnt(6)" ::: "memory");
    else                       asm volatile("s_waitcnt vmcnt(0)" ::: "memory");
  };

  STAGE(0, 0);
  if (nt > 1) { STAGE(1, 1); WAITL(); }
  else        { asm volatile("s_waitcnt vmcnt(0)" ::: "memory"); }
  __builtin_amdgcn_s_barrier();
  __builtin_amdgcn_sched_barrier(0);

  for (int t = 0; t < nt; ++t) {
    const int cur = t % 3;
    if (t + 2 < nt) STAGE((t + 2) % 3, t + 2);
    const f16* Ab = As[cur];
    const f16* Bb = Bs[cur];
    f16x8 bf[FN];
#pragma unroll
    for (int n = 0; n < FN; ++n)
      bf[n] = *(const f16x8*)(Bb + (wn*WTN + n*16 + lrow)*32 + bcol8);
#pragma unroll
    for (int m = 0; m < FM; ++m) {
      f16x8 af = *(const f16x8*)(Ab + (wm*WTM + m*16 + lrow)*32 + bcol8);
#pragma unroll
      for (int n = 0; n < FN; ++n)
        acc[m][n] = __builtin_amdgcn_mfma_f32_16x16x32_f16(af, bf[n], acc[m][n], 0, 0, 0);
    }
    if (t + 1 < nt) {
      if (t + 2 < nt) WAITL();
      else            asm volatile("s_waitcnt vmcnt(0)" ::: "memory");
      __builtin_amdgcn_s_barrier();
      __builtin_amdgcn_sched_barrier(0);
    }
  }

  int crow0 = bm*BM + wm*WTM, ccol0 = bn*BN + wn*WTN;
#pragma unroll
  for (int m = 0; m < FM; ++m)
#pragma unroll
    for (int n = 0; n < FN; ++n) {
      int r0 = crow0 + m*16 + (lane >> 4)*4;
      int c0 = ccol0 + n*16 + (lane & 15);
#pragma unroll
      for (int r = 0; r < 4; ++r) {
        if constexpr (C16) {
          f16* C = (f16*)Cp;
          C[(size_t)(r0 + r)*ldc + c0] = (f16)acc[m][n][r];
        } else {
          float* C = (float*)Cp;
          C[(size_t)(r0 + r)*ldc + c0] = acc[m][n][r];
        }
      }
    }
}

// ------- exact fp32 dt + fused per-chunk cumsum (block = one chunk of 64 rows) -------
__global__ __launch_bounds__(256)
void dt_kernel(const float* __restrict__ x, const float* __restrict__ Win,
               const float* __restrict__ dt_bias, const float* __restrict__ A_log,
               float* __restrict__ dt, float* __restrict__ Acum) {
  __shared__ float xs[64][132];
  __shared__ float ws[128][32];
  __shared__ float dts[64][32];
  int bc = blockIdx.x;
  int r0 = bc * 64;
  int t = threadIdx.x;
  int r = t >> 2, c0 = (t & 3) * 8;
  float acc[8] = {};
  for (int kt = 0; kt < 1024; kt += 128) {
    __syncthreads();
#pragma unroll
    for (int i = 0; i < 8; ++i) {
      int idx4 = t + i*256;
      int rr = idx4 >> 5, c4 = (idx4 & 31) * 4;
      *(f32x4*)&xs[rr][c4] = *(const f32x4*)(x + (size_t)(r0 + rr)*1024 + kt + c4);
    }
#pragma unroll
    for (int i = 0; i < 4; ++i) {
      int idx4 = t + i*256;
      int rr = idx4 >> 3, c4 = (idx4 & 7) * 4;
      *(f32x4*)&ws[rr][c4] = *(const f32x4*)(Win + (size_t)(kt + rr)*NPROJ + DT_OFF + c4);
    }
    __syncthreads();
#pragma unroll 8
    for (int k = 0; k < 128; ++k) {
      float xv = xs[r][k];
      f32x4 w0 = *(const f32x4*)&ws[k][c0];
      f32x4 w1 = *(const f32x4*)&ws[k][c0 + 4];
#pragma unroll
      for (int j = 0; j < 4; ++j) { acc[j] += xv * w0[j]; acc[4+j] += xv * w1[j]; }
    }
  }
#pragma unroll
  for (int j = 0; j < 8; ++j) {
    float v = acc[j] + dt_bias[c0 + j];
    float sp = (v > 20.f) ? v : log1pf(__expf(v));
    dt[(size_t)(r0 + r)*NH + c0 + j] = sp;
    dts[r][c0 + j] = sp;
  }
  __syncthreads();
  // fused acum: per-head inclusive cumsum over the chunk's 64 rows
  int wave = t >> 6, lane = t & 63;
  for (int hh = 0; hh < 8; ++hh) {
    int h = wave*8 + hh;
    float A = -__expf(A_log[h]);
    float v = A * dts[lane][h];
#pragma unroll
    for (int off = 1; off < 64; off <<= 1) {
      float u = __shfl_up(v, off);
      if (lane >= off) v += u;
    }
    Acum[((size_t)bc*NH + h)*64 + lane] = v;
  }
}

// ---------------- causal depthwise conv (k=4) + bias + silu -> fp16 ----------------
__global__ __launch_bounds__(256)
void conv_kernel(const f16* __restrict__ zxh, const float* __restrict__ cw,
                 const float* __restrict__ cb, f16* __restrict__ out) {
  int i = blockIdx.x * 256 + threadIdx.x;      // MROWS * 288
  int row = i / (CONVD/8);
  int c8  = (i - row*(CONVD/8)) * 8;
  int lb = row & (LL - 1);
  f32x4 a0 = *(const f32x4*)(cb + c8);
  f32x4 a1 = *(const f32x4*)(cb + c8 + 4);
#pragma unroll
  for (int j = 0; j < 4; ++j) {
    int lsrc = lb - 3 + j;
    if (lsrc >= 0) {
      f16x8 v = *(const f16x8*)(zxh + (size_t)(row - 3 + j)*NZ + BOFF + c8);
      f32x4 w0 = *(const f32x4*)(cw + j*CONVD + c8);
      f32x4 w1 = *(const f32x4*)(cw + j*CONVD + c8 + 4);
#pragma unroll
      for (int jj = 0; jj < 4; ++jj) {
        a0[jj] += (float)v[jj]   * w0[jj];
        a1[jj] += (float)v[4+jj] * w1[jj];
      }
    }
  }
  f16x8 o;
#pragma unroll
  for (int jj = 0; jj < 4; ++jj) {
    o[jj]   = (f16)silu_f(a0[jj]);
    o[4+jj] = (f16)silu_f(a1[jj]);
  }
  *(f16x8*)(out + (size_t)row*CONVD + c8) = o;
}

// ---------------- G[bc][l][s] = sum_n C[l,n] * B[s,n] (head-independent, f16 out) ----------------
__global__ __launch_bounds__(256)
void gbuf_kernel(const f16* __restrict__ xbc, f16* __restrict__ G) {
  __shared__ float Cs[64][128];
  __shared__ float Bsm[64][128];
  int bc = blockIdx.x;
  int row0 = bc * 64;
  int t = threadIdx.x;
#pragma unroll
  for (int i = 0; i < 4; ++i) {
    int idx = t + i*256;
    int r = idx >> 4, c8 = (idx & 15) * 8;
    f16x8 cv = *(const f16x8*)(xbc + (size_t)(row0 + r)*CONVD + COFF + c8);
    f16x8 bv = *(const f16x8*)(xbc + (size_t)(row0 + r)*CONVD + BOFF + c8);
    f32x4 c0v = {(float)cv[0], (float)cv[1], (float)cv[2], (float)cv[3]};
    f32x4 c1v = {(float)cv[4], (float)cv[5], (float)cv[6], (float)cv[7]};
    f32x4 b0v = {(float)bv[0], (float)bv[1], (float)bv[2], (float)bv[3]};
    f32x4 b1v = {(float)bv[4], (float)bv[5], (float)bv[6], (float)bv[7]};
    *(f32x4*)&Cs[r][c8]      = c0v;  *(f32x4*)&Cs[r][c8 + 4]  = c1v;
    *(f32x4*)&Bsm[r][c8]     = b0v;  *(f32x4*)&Bsm[r][c8 + 4] = b1v;
  }
  __syncthreads();
  int l0 = (t >> 4)*4, s0 = (t & 15)*4;
  float acc[4][4] = {};
  for (int n4 = 0; n4 < 128; n4 += 4) {
    f32x4 cv[4], bv[4];
#pragma unroll
    for (int i = 0; i < 4; ++i) cv[i] = *(const f32x4*)&Cs[l0 + i][n4];
#pragma unroll
    for (int j = 0; j < 4; ++j) bv[j] = *(const f32x4*)&Bsm[s0 + j][n4];
#pragma unroll
    for (int i = 0; i < 4; ++i)
#pragma unroll
      for (int j = 0; j < 4; ++j)
        acc[i][j] += cv[i][0]*bv[j][0] + cv[i][1]*bv[j][1] + cv[i][2]*bv[j][2] + cv[i][3]*bv[j][3];
  }
#pragma unroll
  for (int i = 0; i < 4; ++i) {
    f16x4 v = {(f16)acc[i][0], (f16)acc[i][1], (f16)acc[i][2], (f16)acc[i][3]};
    *(f16x4*)(G + ((size_t)bc*64 + l0 + i)*64 + s0) = v;
  }
}

// ------- per (b,c,h): chunk states only (MFMA) -------
// states[p][n] = sum_l Xd[l][p] * dec[l]*B[l][n]
__global__ __launch_bounds__(256)
void ssd_states_kernel(const f16* __restrict__ xbc, const float* __restrict__ dtb,
                       const float* __restrict__ Acum, f16* __restrict__ states) {
  __shared__ union {
    struct { f16 XdT[64][72]; f16 BT[128][72]; } s;  // 27 KB
    float Sl[64][132];                               // 33.8 KB
  } u;
  __shared__ float ac[64], dts[64];
  int bc = blockIdx.x >> 5, h = blockIdx.x & 31;
  int row0 = bc*64, t = threadIdx.x;
  if (t < 64) {
    ac[t]  = Acum[((size_t)bc*NH + h)*64 + t];
    dts[t] = dtb[(size_t)(row0 + t)*NH + h];
  }
  __syncthreads();
  float ac63 = ac[63];
#pragma unroll
  for (int i = 0; i < 2; ++i) {
    int idx = t + i*256; int l = idx >> 3, p8 = (idx & 7)*8;
    f16x8 v = *(const f16x8*)(xbc + (size_t)(row0 + l)*CONVD + h*HD + p8);
    float d = dts[l];
#pragma unroll
    for (int j = 0; j < 8; ++j) u.s.XdT[p8 + j][l] = (f16)((float)v[j]*d);
  }
#pragma unroll
  for (int i = 0; i < 4; ++i) {
    int idx = t + i*256; int l = idx >> 4, n8 = (idx & 15)*8;
    f16x8 v = *(const f16x8*)(xbc + (size_t)(row0 + l)*CONVD + BOFF + n8);
    float dl = __expf(ac63 - ac[l]);
#pragma unroll
    for (int j = 0; j < 8; ++j) u.s.BT[n8 + j][l] = (f16)((float)v[j]*dl);
  }
  __syncthreads();
  int wave = t >> 6, lane = t & 63;
  int lrow = lane & 15, kgrp = lane >> 4;
  f32x4 sacc[8] = {};
#pragma unroll
  for (int kk = 0; kk < 64; kk += 32) {
    f16x8 afs = *(const f16x8*)&u.s.XdT[wave*16 + lrow][kk + kgrp*8];
#pragma unroll
    for (int n = 0; n < 8; ++n) {
      f16x8 bf = *(const f16x8*)&u.s.BT[n*16 + lrow][kk + kgrp*8];
      sacc[n] = __builtin_amdgcn_mfma_f32_16x16x32_f16(afs, bf, sacc[n], 0, 0, 0);
    }
  }
  __syncthreads();
#pragma unroll
  for (int n = 0; n < 8; ++n)
#pragma unroll
    for (int r = 0; r < 4; ++r)
      u.Sl[wave*16 + kgrp*4 + r][n*16 + lrow] = sacc[n][r];
  __syncthreads();
  size_t sb = ((size_t)bc*NH + h)*8192;
#pragma unroll
  for (int i = 0; i < 4; ++i) {
    int idx = t + i*256; int p = idx >> 4, n8 = (idx & 15)*8;
    f16x8 o;
#pragma unroll
    for (int j = 0; j < 8; ++j) o[j] = (f16)u.Sl[p][n8 + j];
    *(f16x8*)(states + sb + (size_t)p*128 + n8) = o;
  }
}

// ---------------- inter-chunk scan (in place, fp16 storage, fp32 carry) ----------------
__global__ __launch_bounds__(256)
void scan_kernel(f16* __restrict__ states, const float* __restrict__ Acum) {
  int bid = blockIdx.x;
  int bh = bid >> 3, pgrp = bid & 7;
  int b = bh >> 5, h = bh & 31;
  int t = threadIdx.x;
  int p = pgrp*8 + (t >> 5), n4 = (t & 31) * 4;
  size_t off = (size_t)p*128 + n4;
  f32x4 carry = {0.f, 0.f, 0.f, 0.f};
  for (int c = 0; c < NC; ++c) {
    size_t base = ((size_t)(b*NC + c)*NH + h)*8192;
    f16x4 cv = *(f16x4*)(states + base + off);
    f16x4 st;
#pragma unroll
    for (int j = 0; j < 4; ++j) st[j] = (f16)carry[j];
    *(f16x4*)(states + base + off) = st;
    float tc = __expf(Acum[((size_t)(b*NC + c)*NH + h)*64 + 63]);
#pragma unroll
    for (int j = 0; j < 4; ++j) carry[j] = carry[j]*tc + (float)cv[j];
  }
}

// ------- per (b,c,h): Y_diag + Y_off + D-skip + SiLU(z) gating, Ybuf written ONCE -------
__global__ __launch_bounds__(256)
void yoff_kernel(const f16* __restrict__ xbc, const f16* __restrict__ zxh,
                 const f16* __restrict__ Gg, const f16* __restrict__ states,
                 const float* __restrict__ dtb, const float* __restrict__ Acum,
                 const float* __restrict__ Dp, f16* __restrict__ Ybuf) {
  __shared__ union {
    struct { f16 Gt[64][72]; f16 XdT[64][72]; } a;   // 18 KB (ydiag operands)
    struct { f16 Ch[64][136]; f16 Sin[64][136]; } b; // 34 KB (yoff operands)
    float Yl2[64][68];                               // 17 KB (yoff retile)
  } u;
  __shared__ float Yl[64][68];   // 17 KB, ydiag fp32, persists
  __shared__ float ac[64], dts[64], eac[64];
  int bc = blockIdx.x >> 5, h = blockIdx.x & 31;
  int row0 = bc*64, t = threadIdx.x;
  if (t < 64) {
    float a0 = Acum[((size_t)bc*NH + h)*64 + t];
    ac[t]  = a0;
    eac[t] = __expf(a0);
    dts[t] = dtb[(size_t)(row0 + t)*NH + h];
  }
  __syncthreads();
  // stage XdT[p][l] = x[l][p]*dt[l]
#pragma unroll
  for (int i = 0; i < 2; ++i) {
    int idx = t + i*256; int l = idx >> 3, p8 = (idx & 7)*8;
    f16x8 v = *(const f16x8*)(xbc + (size_t)(row0 + l)*CONVD + h*HD + p8);
    float d = dts[l];
#pragma unroll
    for (int j = 0; j < 8; ++j) u.a.XdT[p8 + j][l] = (f16)((float)v[j]*d);
  }
  // stage Gt[l][s] = (l>=s) ? G[l][s]*exp(ac[l]-ac[s]) : 0
#pragma unroll
  for (int i = 0; i < 2; ++i) {
    int idx = t + i*256; int l = idx >> 3, s8 = (idx & 7)*8;
    f16x8 g = *(const f16x8*)(Gg + (size_t)bc*4096 + l*64 + s8);
    float al = ac[l];
    f16x8 o;
#pragma unroll
    for (int j = 0; j < 8; ++j) {
      int s = s8 + j;
      o[j] = (l >= s) ? (f16)((float)g[j] * __expf(al - ac[s])) : (f16)0.f;
    }
    *(f16x8*)&u.a.Gt[l][s8] = o;
  }
  __syncthreads();
  int wave = t >> 6, lane = t & 63;
  int lrow = lane & 15, kgrp = lane >> 4;
  // ydiag MFMA: Y[l][p] = sum_s Gt[l][s] * Xd[s][p]
  f32x4 yacc[4] = {};
#pragma unroll
  for (int kk = 0; kk < 64; kk += 32) {
    f16x8 afy = *(const f16x8*)&u.a.Gt[wave*16 + lrow][kk + kgrp*8];
#pragma unroll
    for (int n = 0; n < 4; ++n) {
      f16x8 bf = *(const f16x8*)&u.a.XdT[n*16 + lrow][kk + kgrp*8];
      yacc[n] = __builtin_amdgcn_mfma_f32_16x16x32_f16(afy, bf, yacc[n], 0, 0, 0);
    }
  }
  __syncthreads();   // union.a reads done -> safe to reuse as union.b
  // retile ydiag into persistent fp32 Yl
#pragma unroll
  for (int n = 0; n < 4; ++n)
#pragma unroll
    for (int r = 0; r < 4; ++r)
      Yl[wave*16 + kgrp*4 + r][n*16 + lrow] = yacc[n][r];
  // stage Ch (C) and Sin (scanned states) into union.b
  size_t sb = ((size_t)bc*NH + h)*8192;
#pragma unroll
  for (int i = 0; i < 4; ++i) {
    int idx = t + i*256; int r = idx >> 4, c8 = (idx & 15)*8;
    *(f16x8*)&u.b.Ch[r][c8]  = *(const f16x8*)(xbc + (size_t)(row0 + r)*CONVD + COFF + c8);
    *(f16x8*)&u.b.Sin[r][c8] = *(const f16x8*)(states + sb + (size_t)r*128 + c8);
  }
  __syncthreads();
  // yoff MFMA: yoffraw[l][p] = sum_n C[l][n] * Sin[p][n]
  f32x4 acc[4] = {};
#pragma unroll
  for (int kk = 0; kk < 128; kk += 32) {
    f16x8 af = *(const f16x8*)&u.b.Ch[wave*16 + lrow][kk + kgrp*8];
#pragma unroll
    for (int n = 0; n < 4; ++n) {
      f16x8 bf = *(const f16x8*)&u.b.Sin[n*16 + lrow][kk + kgrp*8];
      acc[n] = __builtin_amdgcn_mfma_f32_16x16x32_f16(af, bf, acc[n], 0, 0, 0);
    }
  }
  __syncthreads();   // union.b reads done -> safe to reuse as Yl2
#pragma unroll
  for (int n = 0; n < 4; ++n)
#pragma unroll
    for (int r = 0; r < 4; ++r)
      u.Yl2[wave*16 + kgrp*4 + r][n*16 + lrow] = acc[n][r];
  __syncthreads();
  // epilogue: Y = (ydiag + eac*yoffraw + D*x) * silu(z); single Ybuf write
  float Dh = Dp[h];
#pragma unroll
  for (int i = 0; i < 2; ++i) {
    int idx = t + i*256; int l = idx >> 3, p8 = (idx & 7)*8;
    int row = row0 + l;
    f16x8 zh = *(const f16x8*)(zxh + (size_t)row*NZ + h*HD + p8);
    f16x8 xs = *(const f16x8*)(xbc + (size_t)row*CONVD + h*HD + p8);
    float e = eac[l];
    f16x8 o;
#pragma unroll
    for (int j = 0; j < 8; ++j) {
      float yv = Yl[l][p8 + j] + e*u.Yl2[l][p8 + j] + (float)xs[j]*Dh;
      o[j] = (f16)(yv * silu_f((float)zh[j]));
    }
    *(f16x8*)(Ybuf + (size_t)row*DIN + h*HD + p8) = o;
  }
}

// ---------------- RMSNorm + fp16 convert ----------------
__global__ __launch_bounds__(256)
void rms_kernel(const f16* __restrict__ yg, const float* __restrict__ nw,
                f16* __restrict__ yh) {
  __shared__ float red[4];
  int row = blockIdx.x, t = threadIdx.x;
  f16x8 v = *(const f16x8*)(yg + (size_t)row*DIN + t*8);
  float f[8];
  float ss = 0.f;
#pragma unroll
  for (int j = 0; j < 8; ++j) { f[j] = (float)v[j]; ss += f[j]*f[j]; }
#pragma unroll
  for (int off = 32; off > 0; off >>= 1) ss += __shfl_down(ss, off);
  if ((t & 63) == 0) red[t >> 6] = ss;
  __syncthreads();
  float tot = red[0] + red[1] + red[2] + red[3];
  float sc = rsqrtf(tot * (1.f/2048.f) + 1e-5f);
  f32x4 w0 = *(const f32x4*)(nw + t*8);
  f32x4 w1 = *(const f32x4*)(nw + t*8 + 4);
  f16x8 o;
#pragma unroll
  for (int j = 0; j < 4; ++j) {
    o[j]   = (f16)(f[j]   * sc * w0[j]);
    o[4+j] = (f16)(f[4+j] * sc * w1[j]);
  }
  *(f16x8*)(yh + (size_t)row*DIN + t*8) = o;
}

// ---------------- host launcher ----------------
extern "C" void kernel_launch(void* const* d_in, const int* in_sizes, int n_in,
                              void* d_out, int out_size, void* d_ws, size_t ws_size,
                              hipStream_t stream) {
  const float* x       = (const float*)d_in[0];
  const float* W_in    = (const float*)d_in[1];
  const float* conv_w  = (const float*)d_in[2];
  const float* conv_b  = (const float*)d_in[3];
  const float* dt_bias = (const float*)d_in[4];
  const float* A_log   = (const float*)d_in[5];
  const float* Dp      = (const float*)d_in[6];
  const float* norm_w  = (const float*)d_in[7];
  const float* W_out   = (const float*)d_in[8];

  constexpr size_t WS_NEED = 213909504;
  if (ws_size < WS_NEED) return;  // clean fail instead of OOB crash

  char* w = (char*)d_ws;
  f16*   states = (f16*)(w + 0);
  f16*   winT   = (f16*)(w + 0);
  f16*   yh     = (f16*)(w + 0);
  f16*   xh     = (f16*)(w + 33554432);
  f16*   woutT  = (f16*)(w + 33554432);
  f16*   zxh    = (f16*)(w + 67108864);
  f16*   xbcc   = (f16*)(w + 138412032);
  f16*   Ybuf   = (f16*)(w + 176160768);
  float* dtb    = (float*)(w + 209715200);
  float* Acum   = (float*)(w + 210763776);
  f16*   Gg     = (f16*)(w + 211812352);

  tof16_kernel<<<4096, 256, 0, stream>>>(x, xh, MROWS*DM/8);
  transpose_f32_to_f16<<<dim3(NZ/32, DM/32), 256, 0, stream>>>(W_in, winT, DM, NZ, NPROJ);
  gemm_t<256,128,4,2,true><<<(MROWS/256)*(NZ/128), 512, 0, stream>>>(xh, winT, zxh, MROWS, NZ, DM, NZ);
  dt_kernel<<<MROWS/64, 256, 0, stream>>>(x, W_in, dt_bias, A_log, dtb, Acum);
  conv_kernel<<<MROWS*(CONVD/8)/256, 256, 0, stream>>>(zxh, conv_w, conv_b, xbcc);
  gbuf_kernel<<<BB*NC, 256, 0, stream>>>(xbcc, Gg);
  ssd_states_kernel<<<BB*NC*NH, 256, 0, stream>>>(xbcc, dtb, Acum, states);
  scan_kernel<<<BB*NH*8, 256, 0, stream>>>(states, Acum);
  yoff_kernel<<<BB*NC*NH, 256, 0, stream>>>(xbcc, zxh, Gg, states, dtb, Acum, Dp, Ybuf);
  transpose_f32_to_f16<<<dim3(DM/32, DIN/32), 256, 0, stream>>>(W_out, woutT, DIN, DM, DM);
  rms_kernel<<<MROWS, 256, 0, stream>>>(Ybuf, norm_w, yh);
  gemm_t<128,128,2,2,false><<<(MROWS/128)*(DM/128), 256, 0, stream>>>(yh, woutT, d_out, MROWS, DM, DIN, DM);
}

// Round 15
// 430.379 us; speedup vs baseline: 1.0211x; 1.0104x over previous
//
#include <hip/hip_runtime.h>
#include <hip/hip_fp16.h>

typedef _Float16 f16;
typedef _Float16 f16x4 __attribute__((ext_vector_type(4)));
typedef _Float16 f16x8 __attribute__((ext_vector_type(8)));
typedef float f32x4 __attribute__((ext_vector_type(4)));

#define DEV __device__ __forceinline__

// ---- problem constants ----
constexpr int BB    = 2;
constexpr int LL    = 4096;
constexpr int DM    = 1024;
constexpr int DIN   = 2048;
constexpr int DST   = 128;
constexpr int NH    = 32;
constexpr int HD    = 64;
constexpr int NC    = 64;                  // chunks per batch
constexpr int MROWS = BB * LL;             // 8192
constexpr int NPROJ = 2*DIN + 2*DST + NH;  // 4384 (W_in row stride)
constexpr int NZ    = 2*DIN + 2*DST;       // 4352 (z + xBC, GEMM1 N)
constexpr int CONVD = DIN + 2*DST;         // 2304
constexpr int DT_OFF = 2*DIN + 2*DST;      // 4352
constexpr int BOFF  = DIN;                 // 2048 (within NZ / CONVD)
constexpr int COFF  = DIN + DST;           // 2176

DEV float silu_f(float v) { return v / (1.f + __expf(-v)); }

// wave-uniform LDS dest; HW writes lane i at dst + i*16B. Per-lane global src.
DEV void gload_lds16(const f16* gsrc, f16* lds_dst) {
  __builtin_amdgcn_global_load_lds(
      (const __attribute__((address_space(1))) void*)gsrc,
      (__attribute__((address_space(3))) void*)lds_dst, 16, 0, 0);
}

// ---------------- fp32 -> fp16 convert ----------------
__global__ __launch_bounds__(256)
void tof16_kernel(const float* __restrict__ src, f16* __restrict__ dst, int n8) {
  int i = blockIdx.x * 256 + threadIdx.x;
  if (i >= n8) return;
  f32x4 a = *(const f32x4*)(src + (size_t)i*8);
  f32x4 b = *(const f32x4*)(src + (size_t)i*8 + 4);
  f16x8 o;
#pragma unroll
  for (int j = 0; j < 4; ++j) { o[j] = (f16)a[j]; o[4+j] = (f16)b[j]; }
  *(f16x8*)(dst + (size_t)i*8) = o;
}

// ------------- transpose fp32[K rows][srcLd cols] -> fp16[N][K] -------------
// colScale (optional, size K): dst[n][k] = src[k][n] * colScale[k]
__global__ __launch_bounds__(256)
void transpose_f32_to_f16(const float* __restrict__ src, f16* __restrict__ dst,
                          int K, int N, int srcLd, const float* __restrict__ colScale) {
  __shared__ float tbuf[32][33];
  int n0 = blockIdx.x * 32, k0 = blockIdx.y * 32;
  int tx = threadIdx.x & 31, ty = threadIdx.x >> 5;  // 32 x 8
  for (int i = ty; i < 32; i += 8)
    tbuf[i][tx] = src[(size_t)(k0 + i)*srcLd + n0 + tx];
  __syncthreads();
  float cs = colScale ? colScale[k0 + tx] : 1.f;
  for (int i = ty; i < 32; i += 8)
    dst[(size_t)(n0 + i)*K + (k0 + tx)] = (f16)(tbuf[tx][i] * cs);
}

// ------- pipelined MFMA GEMM (R10 proven): C[M][ldc] = A[M][K] * Bt[N][K]^T -------
// BK=32, 3-buffer rotation, stage t+2 ahead, counted vmcnt (never 0 mid-loop).
// LDS <= 72KB keeps 2 blocks/CU (R8 lesson). Plateau ~113us / 28% MfmaUtil.
// R14: T1 XCD-chunked blockIdx swizzle (gridDim.x % 8 == 0 on both launches)
// + optional per-row output scale (RMS fold into gemm2 epilogue).
template<int BM, int BN, int WM_, int WN_, bool C16>
__global__ __launch_bounds__(WM_*WN_*64, 2)
void gemm_t(const f16* __restrict__ A, const f16* __restrict__ Bt,
            void* __restrict__ Cp, int M, int N, int K, int ldc,
            const float* __restrict__ rowScale) {
  constexpr int THREADS = WM_*WN_*64;
  constexpr int WTM = BM/WM_, WTN = BN/WN_;
  constexpr int FM = WTM/16, FN = WTN/16;
  constexpr int LA = BM*4/THREADS, LB = BN*4/THREADS;  // 16B-chunk loads/thread
  constexpr int L = LA + LB;
  __shared__ f16 As[3][BM*32];
  __shared__ f16 Bs[3][BN*32];
  const int nbn = N / BN;
  // XCD-chunked swizzle: XCD k (dispatch round-robin = bid%8) gets a
  // contiguous logical-tile range -> A-panels become L2-resident per XCD.
  const int nwg = (int)gridDim.x;
  const int lb  = ((int)blockIdx.x & 7) * (nwg >> 3) + ((int)blockIdx.x >> 3);
  const int bm = lb / nbn, bn = lb % nbn;
  const int tid = threadIdx.x;
  const int wave = tid >> 6, lane = tid & 63;
  const int lrow = lane & 15, kgrp = lane >> 4;
  const int wm = wave / WN_, wn = wave % WN_;
  const int nt = K >> 5;
  const int bcol8 = (kgrp ^ ((lrow ^ (lrow >> 2)) & 3)) * 8;

  const f16* aptr[LA];
  const f16* bptr[LB];
#pragma unroll
  for (int i = 0; i < LA; ++i) {
    int s = tid + i*THREADS, row = s >> 2;
    int g = (s & 3) ^ ((row ^ (row >> 2)) & 3);
    aptr[i] = A + (size_t)(bm*BM + row)*K + g*8;
  }
#pragma unroll
  for (int i = 0; i < LB; ++i) {
    int s = tid + i*THREADS, row = s >> 2;
    int g = (s & 3) ^ ((row ^ (row >> 2)) & 3);
    bptr[i] = Bt + (size_t)(bn*BN + row)*K + g*8;
  }

  f32x4 acc[FM][FN] = {};

  auto STAGE = [&](int buf, int t) {
#pragma unroll
    for (int i = 0; i < LA; ++i)
      gload_lds16(aptr[i] + (size_t)t*32, As[buf] + (wave*64 + i*THREADS)*8);
#pragma unroll
    for (int i = 0; i < LB; ++i)
      gload_lds16(bptr[i] + (size_t)t*32, Bs[buf] + (wave*64 + i*THREADS)*8);
  };
  auto WAITL = [&]() {
    if constexpr (L == 2)      asm volatile("s_waitcnt vmcnt(2)" ::: "memory");
    else if constexpr (L == 3) asm volatile("s_waitcnt vmcnt(3)" ::: "memory");
    else if constexpr (L == 4) asm volatile("s_waitcnt vmcnt(4)" ::: "memory");
    else if constexpr (L == 6) asm volatile("s_waitcnt vmcnt(6)" ::: "memory");
    else                       asm volatile("s_waitcnt vmcnt(0)" ::: "memory");
  };

  STAGE(0, 0);
  if (nt > 1) { STAGE(1, 1); WAITL(); }
  else        { asm volatile("s_waitcnt vmcnt(0)" ::: "memory"); }
  __builtin_amdgcn_s_barrier();
  __builtin_amdgcn_sched_barrier(0);

  for (int t = 0; t < nt; ++t) {
    const int cur = t % 3;
    if (t + 2 < nt) STAGE((t + 2) % 3, t + 2);
    const f16* Ab = As[cur];
    const f16* Bb = Bs[cur];
    f16x8 bf[FN];
#pragma unroll
    for (int n = 0; n < FN; ++n)
      bf[n] = *(const f16x8*)(Bb + (wn*WTN + n*16 + lrow)*32 + bcol8);
#pragma unroll
    for (int m = 0; m < FM; ++m) {
      f16x8 af = *(const f16x8*)(Ab + (wm*WTM + m*16 + lrow)*32 + bcol8);
#pragma unroll
      for (int n = 0; n < FN; ++n)
        acc[m][n] = __builtin_amdgcn_mfma_f32_16x16x32_f16(af, bf[n], acc[m][n], 0, 0, 0);
    }
    if (t + 1 < nt) {
      if (t + 2 < nt) WAITL();
      else            asm volatile("s_waitcnt vmcnt(0)" ::: "memory");
      __builtin_amdgcn_s_barrier();
      __builtin_amdgcn_sched_barrier(0);
    }
  }

  int crow0 = bm*BM + wm*WTM, ccol0 = bn*BN + wn*WTN;
#pragma unroll
  for (int m = 0; m < FM; ++m)
#pragma unroll
    for (int n = 0; n < FN; ++n) {
      int r0 = crow0 + m*16 + (lane >> 4)*4;
      int c0 = ccol0 + n*16 + (lane & 15);
#pragma unroll
      for (int r = 0; r < 4; ++r) {
        float v = acc[m][n][r];
        if (rowScale) v *= rowScale[r0 + r];
        if constexpr (C16) {
          f16* C = (f16*)Cp;
          C[(size_t)(r0 + r)*ldc + c0] = (f16)v;
        } else {
          float* C = (float*)Cp;
          C[(size_t)(r0 + r)*ldc + c0] = v;
        }
      }
    }
}

// ------- exact fp32 dt + fused per-chunk cumsum (block = one chunk of 64 rows) -------
__global__ __launch_bounds__(256)
void dt_kernel(const float* __restrict__ x, const float* __restrict__ Win,
               const float* __restrict__ dt_bias, const float* __restrict__ A_log,
               float* __restrict__ dt, float* __restrict__ Acum) {
  __shared__ float xs[64][132];
  __shared__ float ws[128][32];
  __shared__ float dts[64][32];
  int bc = blockIdx.x;
  int r0 = bc * 64;
  int t = threadIdx.x;
  int r = t >> 2, c0 = (t & 3) * 8;
  float acc[8] = {};
  for (int kt = 0; kt < 1024; kt += 128) {
    __syncthreads();
#pragma unroll
    for (int i = 0; i < 8; ++i) {
      int idx4 = t + i*256;
      int rr = idx4 >> 5, c4 = (idx4 & 31) * 4;
      *(f32x4*)&xs[rr][c4] = *(const f32x4*)(x + (size_t)(r0 + rr)*1024 + kt + c4);
    }
#pragma unroll
    for (int i = 0; i < 4; ++i) {
      int idx4 = t + i*256;
      int rr = idx4 >> 3, c4 = (idx4 & 7) * 4;
      *(f32x4*)&ws[rr][c4] = *(const f32x4*)(Win + (size_t)(kt + rr)*NPROJ + DT_OFF + c4);
    }
    __syncthreads();
#pragma unroll 8
    for (int k = 0; k < 128; ++k) {
      float xv = xs[r][k];
      f32x4 w0 = *(const f32x4*)&ws[k][c0];
      f32x4 w1 = *(const f32x4*)&ws[k][c0 + 4];
#pragma unroll
      for (int j = 0; j < 4; ++j) { acc[j] += xv * w0[j]; acc[4+j] += xv * w1[j]; }
    }
  }
#pragma unroll
  for (int j = 0; j < 8; ++j) {
    float v = acc[j] + dt_bias[c0 + j];
    float sp = (v > 20.f) ? v : log1pf(__expf(v));
    dt[(size_t)(r0 + r)*NH + c0 + j] = sp;
    dts[r][c0 + j] = sp;
  }
  __syncthreads();
  // fused acum: per-head inclusive cumsum over the chunk's 64 rows
  int wave = t >> 6, lane = t & 63;
  for (int hh = 0; hh < 8; ++hh) {
    int h = wave*8 + hh;
    float A = -__expf(A_log[h]);
    float v = A * dts[lane][h];
#pragma unroll
    for (int off = 1; off < 64; off <<= 1) {
      float u = __shfl_up(v, off);
      if (lane >= off) v += u;
    }
    Acum[((size_t)bc*NH + h)*64 + lane] = v;
  }
}

// ---------------- causal depthwise conv (k=4) + bias + silu -> fp16 ----------------
__global__ __launch_bounds__(256)
void conv_kernel(const f16* __restrict__ zxh, const float* __restrict__ cw,
                 const float* __restrict__ cb, f16* __restrict__ out) {
  int i = blockIdx.x * 256 + threadIdx.x;      // MROWS * 288
  int row = i / (CONVD/8);
  int c8  = (i - row*(CONVD/8)) * 8;
  int lb = row & (LL - 1);
  f32x4 a0 = *(const f32x4*)(cb + c8);
  f32x4 a1 = *(const f32x4*)(cb + c8 + 4);
#pragma unroll
  for (int j = 0; j < 4; ++j) {
    int lsrc = lb - 3 + j;
    if (lsrc >= 0) {
      f16x8 v = *(const f16x8*)(zxh + (size_t)(row - 3 + j)*NZ + BOFF + c8);
      f32x4 w0 = *(const f32x4*)(cw + j*CONVD + c8);
      f32x4 w1 = *(const f32x4*)(cw + j*CONVD + c8 + 4);
#pragma unroll
      for (int jj = 0; jj < 4; ++jj) {
        a0[jj] += (float)v[jj]   * w0[jj];
        a1[jj] += (float)v[4+jj] * w1[jj];
      }
    }
  }
  f16x8 o;
#pragma unroll
  for (int jj = 0; jj < 4; ++jj) {
    o[jj]   = (f16)silu_f(a0[jj]);
    o[4+jj] = (f16)silu_f(a1[jj]);
  }
  *(f16x8*)(out + (size_t)row*CONVD + c8) = o;
}

// ---------------- G[bc][l][s] = sum_n C[l,n] * B[s,n] (head-independent, f16 out) ----------------
__global__ __launch_bounds__(256)
void gbuf_kernel(const f16* __restrict__ xbc, f16* __restrict__ G) {
  __shared__ float Cs[64][128];
  __shared__ float Bsm[64][128];
  int bc = blockIdx.x;
  int row0 = bc * 64;
  int t = threadIdx.x;
#pragma unroll
  for (int i = 0; i < 4; ++i) {
    int idx = t + i*256;
    int r = idx >> 4, c8 = (idx & 15) * 8;
    f16x8 cv = *(const f16x8*)(xbc + (size_t)(row0 + r)*CONVD + COFF + c8);
    f16x8 bv = *(const f16x8*)(xbc + (size_t)(row0 + r)*CONVD + BOFF + c8);
    f32x4 c0v = {(float)cv[0], (float)cv[1], (float)cv[2], (float)cv[3]};
    f32x4 c1v = {(float)cv[4], (float)cv[5], (float)cv[6], (float)cv[7]};
    f32x4 b0v = {(float)bv[0], (float)bv[1], (float)bv[2], (float)bv[3]};
    f32x4 b1v = {(float)bv[4], (float)bv[5], (float)bv[6], (float)bv[7]};
    *(f32x4*)&Cs[r][c8]      = c0v;  *(f32x4*)&Cs[r][c8 + 4]  = c1v;
    *(f32x4*)&Bsm[r][c8]     = b0v;  *(f32x4*)&Bsm[r][c8 + 4] = b1v;
  }
  __syncthreads();
  int l0 = (t >> 4)*4, s0 = (t & 15)*4;
  float acc[4][4] = {};
  for (int n4 = 0; n4 < 128; n4 += 4) {
    f32x4 cv[4], bv[4];
#pragma unroll
    for (int i = 0; i < 4; ++i) cv[i] = *(const f32x4*)&Cs[l0 + i][n4];
#pragma unroll
    for (int j = 0; j < 4; ++j) bv[j] = *(const f32x4*)&Bsm[s0 + j][n4];
#pragma unroll
    for (int i = 0; i < 4; ++i)
#pragma unroll
      for (int j = 0; j < 4; ++j)
        acc[i][j] += cv[i][0]*bv[j][0] + cv[i][1]*bv[j][1] + cv[i][2]*bv[j][2] + cv[i][3]*bv[j][3];
  }
#pragma unroll
  for (int i = 0; i < 4; ++i) {
    f16x4 v = {(f16)acc[i][0], (f16)acc[i][1], (f16)acc[i][2], (f16)acc[i][3]};
    *(f16x4*)(G + ((size_t)bc*64 + l0 + i)*64 + s0) = v;
  }
}

// ------- per (b,c,h): chunk states only (MFMA) -------
// states[p][n] = sum_l Xd[l][p] * dec[l]*B[l][n]
__global__ __launch_bounds__(256)
void ssd_states_kernel(const f16* __restrict__ xbc, const float* __restrict__ dtb,
                       const float* __restrict__ Acum, f16* __restrict__ states) {
  __shared__ union {
    struct { f16 XdT[64][72]; f16 BT[128][72]; } s;  // 27 KB
    float Sl[64][132];                               // 33.8 KB
  } u;
  __shared__ float ac[64], dts[64];
  int bc = blockIdx.x >> 5, h = blockIdx.x & 31;
  int row0 = bc*64, t = threadIdx.x;
  if (t < 64) {
    ac[t]  = Acum[((size_t)bc*NH + h)*64 + t];
    dts[t] = dtb[(size_t)(row0 + t)*NH + h];
  }
  __syncthreads();
  float ac63 = ac[63];
#pragma unroll
  for (int i = 0; i < 2; ++i) {
    int idx = t + i*256; int l = idx >> 3, p8 = (idx & 7)*8;
    f16x8 v = *(const f16x8*)(xbc + (size_t)(row0 + l)*CONVD + h*HD + p8);
    float d = dts[l];
#pragma unroll
    for (int j = 0; j < 8; ++j) u.s.XdT[p8 + j][l] = (f16)((float)v[j]*d);
  }
#pragma unroll
  for (int i = 0; i < 4; ++i) {
    int idx = t + i*256; int l = idx >> 4, n8 = (idx & 15)*8;
    f16x8 v = *(const f16x8*)(xbc + (size_t)(row0 + l)*CONVD + BOFF + n8);
    float dl = __expf(ac63 - ac[l]);
#pragma unroll
    for (int j = 0; j < 8; ++j) u.s.BT[n8 + j][l] = (f16)((float)v[j]*dl);
  }
  __syncthreads();
  int wave = t >> 6, lane = t & 63;
  int lrow = lane & 15, kgrp = lane >> 4;
  f32x4 sacc[8] = {};
#pragma unroll
  for (int kk = 0; kk < 64; kk += 32) {
    f16x8 afs = *(const f16x8*)&u.s.XdT[wave*16 + lrow][kk + kgrp*8];
#pragma unroll
    for (int n = 0; n < 8; ++n) {
      f16x8 bf = *(const f16x8*)&u.s.BT[n*16 + lrow][kk + kgrp*8];
      sacc[n] = __builtin_amdgcn_mfma_f32_16x16x32_f16(afs, bf, sacc[n], 0, 0, 0);
    }
  }
  __syncthreads();
#pragma unroll
  for (int n = 0; n < 8; ++n)
#pragma unroll
    for (int r = 0; r < 4; ++r)
      u.Sl[wave*16 + kgrp*4 + r][n*16 + lrow] = sacc[n][r];
  __syncthreads();
  size_t sb = ((size_t)bc*NH + h)*8192;
#pragma unroll
  for (int i = 0; i < 4; ++i) {
    int idx = t + i*256; int p = idx >> 4, n8 = (idx & 15)*8;
    f16x8 o;
#pragma unroll
    for (int j = 0; j < 8; ++j) o[j] = (f16)u.Sl[p][n8 + j];
    *(f16x8*)(states + sb + (size_t)p*128 + n8) = o;
  }
}

// ---------------- inter-chunk scan (in place, fp16 storage, fp32 carry) ----------------
__global__ __launch_bounds__(256)
void scan_kernel(f16* __restrict__ states, const float* __restrict__ Acum) {
  int bid = blockIdx.x;
  int bh = bid >> 3, pgrp = bid & 7;
  int b = bh >> 5, h = bh & 31;
  int t = threadIdx.x;
  int p = pgrp*8 + (t >> 5), n4 = (t & 31) * 4;
  size_t off = (size_t)p*128 + n4;
  f32x4 carry = {0.f, 0.f, 0.f, 0.f};
  for (int c = 0; c < NC; ++c) {
    size_t base = ((size_t)(b*NC + c)*NH + h)*8192;
    f16x4 cv = *(f16x4*)(states + base + off);
    f16x4 st;
#pragma unroll
    for (int j = 0; j < 4; ++j) st[j] = (f16)carry[j];
    *(f16x4*)(states + base + off) = st;
    float tc = __expf(Acum[((size_t)(b*NC + c)*NH + h)*64 + 63]);
#pragma unroll
    for (int j = 0; j < 4; ++j) carry[j] = carry[j]*tc + (float)cv[j];
  }
}

// ------- per (b,c,h): Y_diag + Y_off + D-skip + SiLU(z) gating, Ybuf written ONCE -------
__global__ __launch_bounds__(256)
void yoff_kernel(const f16* __restrict__ xbc, const f16* __restrict__ zxh,
                 const f16* __restrict__ Gg, const f16* __restrict__ states,
                 const float* __restrict__ dtb, const float* __restrict__ Acum,
                 const float* __restrict__ Dp, f16* __restrict__ Ybuf) {
  __shared__ union {
    struct { f16 Gt[64][72]; f16 XdT[64][72]; } a;   // 18 KB (ydiag operands)
    struct { f16 Ch[64][136]; f16 Sin[64][136]; } b; // 34 KB (yoff operands)
    float Yl2[64][68];                               // 17 KB (yoff retile)
  } u;
  __shared__ float Yl[64][68];   // 17 KB, ydiag fp32, persists
  __shared__ float ac[64], dts[64], eac[64];
  int bc = blockIdx.x >> 5, h = blockIdx.x & 31;
  int row0 = bc*64, t = threadIdx.x;
  if (t < 64) {
    float a0 = Acum[((size_t)bc*NH + h)*64 + t];
    ac[t]  = a0;
    eac[t] = __expf(a0);
    dts[t] = dtb[(size_t)(row0 + t)*NH + h];
  }
  __syncthreads();
  // stage XdT[p][l] = x[l][p]*dt[l]
#pragma unroll
  for (int i = 0; i < 2; ++i) {
    int idx = t + i*256; int l = idx >> 3, p8 = (idx & 7)*8;
    f16x8 v = *(const f16x8*)(xbc + (size_t)(row0 + l)*CONVD + h*HD + p8);
    float d = dts[l];
#pragma unroll
    for (int j = 0; j < 8; ++j) u.a.XdT[p8 + j][l] = (f16)((float)v[j]*d);
  }
  // stage Gt[l][s] = (l>=s) ? G[l][s]*exp(ac[l]-ac[s]) : 0
#pragma unroll
  for (int i = 0; i < 2; ++i) {
    int idx = t + i*256; int l = idx >> 3, s8 = (idx & 7)*8;
    f16x8 g = *(const f16x8*)(Gg + (size_t)bc*4096 + l*64 + s8);
    float al = ac[l];
    f16x8 o;
#pragma unroll
    for (int j = 0; j < 8; ++j) {
      int s = s8 + j;
      o[j] = (l >= s) ? (f16)((float)g[j] * __expf(al - ac[s])) : (f16)0.f;
    }
    *(f16x8*)&u.a.Gt[l][s8] = o;
  }
  __syncthreads();
  int wave = t >> 6, lane = t & 63;
  int lrow = lane & 15, kgrp = lane >> 4;
  // ydiag MFMA: Y[l][p] = sum_s Gt[l][s] * Xd[s][p]
  f32x4 yacc[4] = {};
#pragma unroll
  for (int kk = 0; kk < 64; kk += 32) {
    f16x8 afy = *(const f16x8*)&u.a.Gt[wave*16 + lrow][kk + kgrp*8];
#pragma unroll
    for (int n = 0; n < 4; ++n) {
      f16x8 bf = *(const f16x8*)&u.a.XdT[n*16 + lrow][kk + kgrp*8];
      yacc[n] = __builtin_amdgcn_mfma_f32_16x16x32_f16(afy, bf, yacc[n], 0, 0, 0);
    }
  }
  __syncthreads();   // union.a reads done -> safe to reuse as union.b
  // retile ydiag into persistent fp32 Yl
#pragma unroll
  for (int n = 0; n < 4; ++n)
#pragma unroll
    for (int r = 0; r < 4; ++r)
      Yl[wave*16 + kgrp*4 + r][n*16 + lrow] = yacc[n][r];
  // stage Ch (C) and Sin (scanned states) into union.b
  size_t sb = ((size_t)bc*NH + h)*8192;
#pragma unroll
  for (int i = 0; i < 4; ++i) {
    int idx = t + i*256; int r = idx >> 4, c8 = (idx & 15)*8;
    *(f16x8*)&u.b.Ch[r][c8]  = *(const f16x8*)(xbc + (size_t)(row0 + r)*CONVD + COFF + c8);
    *(f16x8*)&u.b.Sin[r][c8] = *(const f16x8*)(states + sb + (size_t)r*128 + c8);
  }
  __syncthreads();
  // yoff MFMA: yoffraw[l][p] = sum_n C[l][n] * Sin[p][n]
  f32x4 acc[4] = {};
#pragma unroll
  for (int kk = 0; kk < 128; kk += 32) {
    f16x8 af = *(const f16x8*)&u.b.Ch[wave*16 + lrow][kk + kgrp*8];
#pragma unroll
    for (int n = 0; n < 4; ++n) {
      f16x8 bf = *(const f16x8*)&u.b.Sin[n*16 + lrow][kk + kgrp*8];
      acc[n] = __builtin_amdgcn_mfma_f32_16x16x32_f16(af, bf, acc[n], 0, 0, 0);
    }
  }
  __syncthreads();   // union.b reads done -> safe to reuse as Yl2
#pragma unroll
  for (int n = 0; n < 4; ++n)
#pragma unroll
    for (int r = 0; r < 4; ++r)
      u.Yl2[wave*16 + kgrp*4 + r][n*16 + lrow] = acc[n][r];
  __syncthreads();
  // epilogue: Y = (ydiag + eac*yoffraw + D*x) * silu(z); single Ybuf write
  float Dh = Dp[h];
#pragma unroll
  for (int i = 0; i < 2; ++i) {
    int idx = t + i*256; int l = idx >> 3, p8 = (idx & 7)*8;
    int row = row0 + l;
    f16x8 zh = *(const f16x8*)(zxh + (size_t)row*NZ + h*HD + p8);
    f16x8 xs = *(const f16x8*)(xbc + (size_t)row*CONVD + h*HD + p8);
    float e = eac[l];
    f16x8 o;
#pragma unroll
    for (int j = 0; j < 8; ++j) {
      float yv = Yl[l][p8 + j] + e*u.Yl2[l][p8 + j] + (float)xs[j]*Dh;
      o[j] = (f16)(yv * silu_f((float)zh[j]));
    }
    *(f16x8*)(Ybuf + (size_t)row*DIN + h*HD + p8) = o;
  }
}

// ------- RMS scale only: scale[row] = rsqrt(mean(Ybuf[row]^2)+eps) -------
// (norm_w folded into woutT; scale applied in gemm2 epilogue)
__global__ __launch_bounds__(256)
void rms_scale_kernel(const f16* __restrict__ yg, float* __restrict__ scale) {
  __shared__ float red[4];
  int row = blockIdx.x, t = threadIdx.x;
  f16x8 v = *(const f16x8*)(yg + (size_t)row*DIN + t*8);
  float ss = 0.f;
#pragma unroll
  for (int j = 0; j < 8; ++j) { float f = (float)v[j]; ss += f*f; }
#pragma unroll
  for (int off = 32; off > 0; off >>= 1) ss += __shfl_down(ss, off);
  if ((t & 63) == 0) red[t >> 6] = ss;
  __syncthreads();
  if (t == 0) {
    float tot = red[0] + red[1] + red[2] + red[3];
    scale[row] = rsqrtf(tot * (1.f/2048.f) + 1e-5f);
  }
}

// ---------------- host launcher ----------------
extern "C" void kernel_launch(void* const* d_in, const int* in_sizes, int n_in,
                              void* d_out, int out_size, void* d_ws, size_t ws_size,
                              hipStream_t stream) {
  const float* x       = (const float*)d_in[0];
  const float* W_in    = (const float*)d_in[1];
  const float* conv_w  = (const float*)d_in[2];
  const float* conv_b  = (const float*)d_in[3];
  const float* dt_bias = (const float*)d_in[4];
  const float* A_log   = (const float*)d_in[5];
  const float* Dp      = (const float*)d_in[6];
  const float* norm_w  = (const float*)d_in[7];
  const float* W_out   = (const float*)d_in[8];

  constexpr size_t WS_NEED = 213909504;
  if (ws_size < WS_NEED) return;  // clean fail instead of OOB crash

  char* w = (char*)d_ws;
  f16*   states = (f16*)(w + 0);
  f16*   winT   = (f16*)(w + 0);
  f16*   xh     = (f16*)(w + 33554432);
  f16*   woutT  = (f16*)(w + 33554432);
  f16*   zxh    = (f16*)(w + 67108864);
  f16*   xbcc   = (f16*)(w + 138412032);
  f16*   Ybuf   = (f16*)(w + 176160768);
  float* dtb    = (float*)(w + 209715200);
  float* Acum   = (float*)(w + 210763776);
  f16*   Gg     = (f16*)(w + 211812352);
  float* rscale = (float*)(w + 212860928);   // 32 KB

  tof16_kernel<<<4096, 256, 0, stream>>>(x, xh, MROWS*DM/8);
  transpose_f32_to_f16<<<dim3(NZ/32, DM/32), 256, 0, stream>>>(W_in, winT, DM, NZ, NPROJ, nullptr);
  gemm_t<256,128,4,2,true><<<(MROWS/256)*(NZ/128), 512, 0, stream>>>(xh, winT, zxh, MROWS, NZ, DM, NZ, nullptr);
  dt_kernel<<<MROWS/64, 256, 0, stream>>>(x, W_in, dt_bias, A_log, dtb, Acum);
  conv_kernel<<<MROWS*(CONVD/8)/256, 256, 0, stream>>>(zxh, conv_w, conv_b, xbcc);
  gbuf_kernel<<<BB*NC, 256, 0, stream>>>(xbcc, Gg);
  ssd_states_kernel<<<BB*NC*NH, 256, 0, stream>>>(xbcc, dtb, Acum, states);
  scan_kernel<<<BB*NH*8, 256, 0, stream>>>(states, Acum);
  yoff_kernel<<<BB*NC*NH, 256, 0, stream>>>(xbcc, zxh, Gg, states, dtb, Acum, Dp, Ybuf);
  transpose_f32_to_f16<<<dim3(DM/32, DIN/32), 256, 0, stream>>>(W_out, woutT, DIN, DM, DM, norm_w);
  rms_scale_kernel<<<MROWS, 256, 0, stream>>>(Ybuf, rscale);
  gemm_t<128,128,2,2,false><<<(MROWS/128)*(DM/128), 256, 0, stream>>>(Ybuf, woutT, d_out, MROWS, DM, DIN, DM, rscale);
}

// Round 16
// 425.996 us; speedup vs baseline: 1.0316x; 1.0103x over previous
//
#include <hip/hip_runtime.h>
#include <hip/hip_fp16.h>

typedef _Float16 f16;
typedef _Float16 f16x4 __attribute__((ext_vector_type(4)));
typedef _Float16 f16x8 __attribute__((ext_vector_type(8)));
typedef float f32x4 __attribute__((ext_vector_type(4)));

#define DEV __device__ __forceinline__

// ---- problem constants ----
constexpr int BB    = 2;
constexpr int LL    = 4096;
constexpr int DM    = 1024;
constexpr int DIN   = 2048;
constexpr int DST   = 128;
constexpr int NH    = 32;
constexpr int HD    = 64;
constexpr int NC    = 64;                  // chunks per batch
constexpr int MROWS = BB * LL;             // 8192
constexpr int NPROJ = 2*DIN + 2*DST + NH;  // 4384 (W_in row stride)
constexpr int NZ    = 2*DIN + 2*DST;       // 4352 (z + xBC, GEMM1 N)
constexpr int CONVD = DIN + 2*DST;         // 2304
constexpr int DT_OFF = 2*DIN + 2*DST;      // 4352
constexpr int BOFF  = DIN;                 // 2048 (within NZ / CONVD)
constexpr int COFF  = DIN + DST;           // 2176

DEV float silu_f(float v) { return v / (1.f + __expf(-v)); }

// wave-uniform LDS dest; HW writes lane i at dst + i*16B. Per-lane global src.
DEV void gload_lds16(const f16* gsrc, f16* lds_dst) {
  __builtin_amdgcn_global_load_lds(
      (const __attribute__((address_space(1))) void*)gsrc,
      (__attribute__((address_space(3))) void*)lds_dst, 16, 0, 0);
}

// ---------------- fp32 -> fp16 convert ----------------
__global__ __launch_bounds__(256)
void tof16_kernel(const float* __restrict__ src, f16* __restrict__ dst, int n8) {
  int i = blockIdx.x * 256 + threadIdx.x;
  if (i >= n8) return;
  f32x4 a = *(const f32x4*)(src + (size_t)i*8);
  f32x4 b = *(const f32x4*)(src + (size_t)i*8 + 4);
  f16x8 o;
#pragma unroll
  for (int j = 0; j < 4; ++j) { o[j] = (f16)a[j]; o[4+j] = (f16)b[j]; }
  *(f16x8*)(dst + (size_t)i*8) = o;
}

// ------------- transpose fp32[K rows][srcLd cols] -> fp16[N][K] -------------
// colScale (optional, size K): dst[n][k] = src[k][n] * colScale[k]
__global__ __launch_bounds__(256)
void transpose_f32_to_f16(const float* __restrict__ src, f16* __restrict__ dst,
                          int K, int N, int srcLd, const float* __restrict__ colScale) {
  __shared__ float tbuf[32][33];
  int n0 = blockIdx.x * 32, k0 = blockIdx.y * 32;
  int tx = threadIdx.x & 31, ty = threadIdx.x >> 5;  // 32 x 8
  for (int i = ty; i < 32; i += 8)
    tbuf[i][tx] = src[(size_t)(k0 + i)*srcLd + n0 + tx];
  __syncthreads();
  float cs = colScale ? colScale[k0 + tx] : 1.f;
  for (int i = ty; i < 32; i += 8)
    dst[(size_t)(n0 + i)*K + (k0 + tx)] = (f16)(tbuf[tx][i] * cs);
}

// ------- pipelined MFMA GEMM: C[M][ldc] = A[M][K] * Bt[N][K]^T -------
// R16: 2-buffer LDS (48KB gemm1 -> 3 blocks/CU, vs R10's 3-buffer 72KB @ 2
// blocks/CU). Boundary = vmcnt(0)+barrier; stage(t+1) issued BEFORE compute(t)
// so MFMA stream + extra co-resident block cover the drain (m97/m103 regime).
// XCD-chunked swizzle kept (FETCH 110->90MB measured R15); optional rowScale.
template<int BM, int BN, int WM_, int WN_, bool C16>
__global__ __launch_bounds__(WM_*WN_*64, 2)
void gemm_t(const f16* __restrict__ A, const f16* __restrict__ Bt,
            void* __restrict__ Cp, int M, int N, int K, int ldc,
            const float* __restrict__ rowScale) {
  constexpr int THREADS = WM_*WN_*64;
  constexpr int WTM = BM/WM_, WTN = BN/WN_;
  constexpr int FM = WTM/16, FN = WTN/16;
  constexpr int LA = BM*4/THREADS, LB = BN*4/THREADS;  // 16B-chunk loads/thread
  __shared__ f16 As[2][BM*32];
  __shared__ f16 Bs[2][BN*32];
  const int nbn = N / BN;
  const int nwg = (int)gridDim.x;
  const int lb  = ((int)blockIdx.x & 7) * (nwg >> 3) + ((int)blockIdx.x >> 3);
  const int bm = lb / nbn, bn = lb % nbn;
  const int tid = threadIdx.x;
  const int wave = tid >> 6, lane = tid & 63;
  const int lrow = lane & 15, kgrp = lane >> 4;
  const int wm = wave / WN_, wn = wave % WN_;
  const int nt = K >> 5;
  const int bcol8 = (kgrp ^ ((lrow ^ (lrow >> 2)) & 3)) * 8;

  const f16* aptr[LA];
  const f16* bptr[LB];
#pragma unroll
  for (int i = 0; i < LA; ++i) {
    int s = tid + i*THREADS, row = s >> 2;
    int g = (s & 3) ^ ((row ^ (row >> 2)) & 3);
    aptr[i] = A + (size_t)(bm*BM + row)*K + g*8;
  }
#pragma unroll
  for (int i = 0; i < LB; ++i) {
    int s = tid + i*THREADS, row = s >> 2;
    int g = (s & 3) ^ ((row ^ (row >> 2)) & 3);
    bptr[i] = Bt + (size_t)(bn*BN + row)*K + g*8;
  }

  f32x4 acc[FM][FN] = {};

  auto STAGE = [&](int buf, int t) {
#pragma unroll
    for (int i = 0; i < LA; ++i)
      gload_lds16(aptr[i] + (size_t)t*32, As[buf] + (wave*64 + i*THREADS)*8);
#pragma unroll
    for (int i = 0; i < LB; ++i)
      gload_lds16(bptr[i] + (size_t)t*32, Bs[buf] + (wave*64 + i*THREADS)*8);
  };

  STAGE(0, 0);
  asm volatile("s_waitcnt vmcnt(0)" ::: "memory");
  __builtin_amdgcn_s_barrier();
  __builtin_amdgcn_sched_barrier(0);

  for (int t = 0; t < nt; ++t) {
    const int cur = t & 1;
    if (t + 1 < nt) STAGE(cur ^ 1, t + 1);
    const f16* Ab = As[cur];
    const f16* Bb = Bs[cur];
    f16x8 bf[FN];
#pragma unroll
    for (int n = 0; n < FN; ++n)
      bf[n] = *(const f16x8*)(Bb + (wn*WTN + n*16 + lrow)*32 + bcol8);
#pragma unroll
    for (int m = 0; m < FM; ++m) {
      f16x8 af = *(const f16x8*)(Ab + (wm*WTM + m*16 + lrow)*32 + bcol8);
#pragma unroll
      for (int n = 0; n < FN; ++n)
        acc[m][n] = __builtin_amdgcn_mfma_f32_16x16x32_f16(af, bf[n], acc[m][n], 0, 0, 0);
    }
    if (t + 1 < nt) {
      asm volatile("s_waitcnt vmcnt(0)" ::: "memory");
      __builtin_amdgcn_s_barrier();
      __builtin_amdgcn_sched_barrier(0);
    }
  }

  int crow0 = bm*BM + wm*WTM, ccol0 = bn*BN + wn*WTN;
#pragma unroll
  for (int m = 0; m < FM; ++m)
#pragma unroll
    for (int n = 0; n < FN; ++n) {
      int r0 = crow0 + m*16 + (lane >> 4)*4;
      int c0 = ccol0 + n*16 + (lane & 15);
#pragma unroll
      for (int r = 0; r < 4; ++r) {
        float v = acc[m][n][r];
        if (rowScale) v *= rowScale[r0 + r];
        if constexpr (C16) {
          f16* C = (f16*)Cp;
          C[(size_t)(r0 + r)*ldc + c0] = (f16)v;
        } else {
          float* C = (float*)Cp;
          C[(size_t)(r0 + r)*ldc + c0] = v;
        }
      }
    }
}

// ------- exact fp32 dt + fused per-chunk cumsum (block = one chunk of 64 rows) -------
__global__ __launch_bounds__(256)
void dt_kernel(const float* __restrict__ x, const float* __restrict__ Win,
               const float* __restrict__ dt_bias, const float* __restrict__ A_log,
               float* __restrict__ dt, float* __restrict__ Acum) {
  __shared__ float xs[64][132];
  __shared__ float ws[128][32];
  __shared__ float dts[64][32];
  int bc = blockIdx.x;
  int r0 = bc * 64;
  int t = threadIdx.x;
  int r = t >> 2, c0 = (t & 3) * 8;
  float acc[8] = {};
  for (int kt = 0; kt < 1024; kt += 128) {
    __syncthreads();
#pragma unroll
    for (int i = 0; i < 8; ++i) {
      int idx4 = t + i*256;
      int rr = idx4 >> 5, c4 = (idx4 & 31) * 4;
      *(f32x4*)&xs[rr][c4] = *(const f32x4*)(x + (size_t)(r0 + rr)*1024 + kt + c4);
    }
#pragma unroll
    for (int i = 0; i < 4; ++i) {
      int idx4 = t + i*256;
      int rr = idx4 >> 3, c4 = (idx4 & 7) * 4;
      *(f32x4*)&ws[rr][c4] = *(const f32x4*)(Win + (size_t)(kt + rr)*NPROJ + DT_OFF + c4);
    }
    __syncthreads();
#pragma unroll 8
    for (int k = 0; k < 128; ++k) {
      float xv = xs[r][k];
      f32x4 w0 = *(const f32x4*)&ws[k][c0];
      f32x4 w1 = *(const f32x4*)&ws[k][c0 + 4];
#pragma unroll
      for (int j = 0; j < 4; ++j) { acc[j] += xv * w0[j]; acc[4+j] += xv * w1[j]; }
    }
  }
#pragma unroll
  for (int j = 0; j < 8; ++j) {
    float v = acc[j] + dt_bias[c0 + j];
    float sp = (v > 20.f) ? v : log1pf(__expf(v));
    dt[(size_t)(r0 + r)*NH + c0 + j] = sp;
    dts[r][c0 + j] = sp;
  }
  __syncthreads();
  // fused acum: per-head inclusive cumsum over the chunk's 64 rows
  int wave = t >> 6, lane = t & 63;
  for (int hh = 0; hh < 8; ++hh) {
    int h = wave*8 + hh;
    float A = -__expf(A_log[h]);
    float v = A * dts[lane][h];
#pragma unroll
    for (int off = 1; off < 64; off <<= 1) {
      float u = __shfl_up(v, off);
      if (lane >= off) v += u;
    }
    Acum[((size_t)bc*NH + h)*64 + lane] = v;
  }
}

// ---------------- causal depthwise conv (k=4) + bias + silu -> fp16 ----------------
__global__ __launch_bounds__(256)
void conv_kernel(const f16* __restrict__ zxh, const float* __restrict__ cw,
                 const float* __restrict__ cb, f16* __restrict__ out) {
  int i = blockIdx.x * 256 + threadIdx.x;      // MROWS * 288
  int row = i / (CONVD/8);
  int c8  = (i - row*(CONVD/8)) * 8;
  int lb = row & (LL - 1);
  f32x4 a0 = *(const f32x4*)(cb + c8);
  f32x4 a1 = *(const f32x4*)(cb + c8 + 4);
#pragma unroll
  for (int j = 0; j < 4; ++j) {
    int lsrc = lb - 3 + j;
    if (lsrc >= 0) {
      f16x8 v = *(const f16x8*)(zxh + (size_t)(row - 3 + j)*NZ + BOFF + c8);
      f32x4 w0 = *(const f32x4*)(cw + j*CONVD + c8);
      f32x4 w1 = *(const f32x4*)(cw + j*CONVD + c8 + 4);
#pragma unroll
      for (int jj = 0; jj < 4; ++jj) {
        a0[jj] += (float)v[jj]   * w0[jj];
        a1[jj] += (float)v[4+jj] * w1[jj];
      }
    }
  }
  f16x8 o;
#pragma unroll
  for (int jj = 0; jj < 4; ++jj) {
    o[jj]   = (f16)silu_f(a0[jj]);
    o[4+jj] = (f16)silu_f(a1[jj]);
  }
  *(f16x8*)(out + (size_t)row*CONVD + c8) = o;
}

// ---------------- G[bc][l][s] = sum_n C[l,n] * B[s,n] (head-independent, f16 out) ----------------
__global__ __launch_bounds__(256)
void gbuf_kernel(const f16* __restrict__ xbc, f16* __restrict__ G) {
  __shared__ float Cs[64][128];
  __shared__ float Bsm[64][128];
  int bc = blockIdx.x;
  int row0 = bc * 64;
  int t = threadIdx.x;
#pragma unroll
  for (int i = 0; i < 4; ++i) {
    int idx = t + i*256;
    int r = idx >> 4, c8 = (idx & 15) * 8;
    f16x8 cv = *(const f16x8*)(xbc + (size_t)(row0 + r)*CONVD + COFF + c8);
    f16x8 bv = *(const f16x8*)(xbc + (size_t)(row0 + r)*CONVD + BOFF + c8);
    f32x4 c0v = {(float)cv[0], (float)cv[1], (float)cv[2], (float)cv[3]};
    f32x4 c1v = {(float)cv[4], (float)cv[5], (float)cv[6], (float)cv[7]};
    f32x4 b0v = {(float)bv[0], (float)bv[1], (float)bv[2], (float)bv[3]};
    f32x4 b1v = {(float)bv[4], (float)bv[5], (float)bv[6], (float)bv[7]};
    *(f32x4*)&Cs[r][c8]      = c0v;  *(f32x4*)&Cs[r][c8 + 4]  = c1v;
    *(f32x4*)&Bsm[r][c8]     = b0v;  *(f32x4*)&Bsm[r][c8 + 4] = b1v;
  }
  __syncthreads();
  int l0 = (t >> 4)*4, s0 = (t & 15)*4;
  float acc[4][4] = {};
  for (int n4 = 0; n4 < 128; n4 += 4) {
    f32x4 cv[4], bv[4];
#pragma unroll
    for (int i = 0; i < 4; ++i) cv[i] = *(const f32x4*)&Cs[l0 + i][n4];
#pragma unroll
    for (int j = 0; j < 4; ++j) bv[j] = *(const f32x4*)&Bsm[s0 + j][n4];
#pragma unroll
    for (int i = 0; i < 4; ++i)
#pragma unroll
      for (int j = 0; j < 4; ++j)
        acc[i][j] += cv[i][0]*bv[j][0] + cv[i][1]*bv[j][1] + cv[i][2]*bv[j][2] + cv[i][3]*bv[j][3];
  }
#pragma unroll
  for (int i = 0; i < 4; ++i) {
    f16x4 v = {(f16)acc[i][0], (f16)acc[i][1], (f16)acc[i][2], (f16)acc[i][3]};
    *(f16x4*)(G + ((size_t)bc*64 + l0 + i)*64 + s0) = v;
  }
}

// ------- per (b,c,h): chunk states only (MFMA) -------
// states[p][n] = sum_l Xd[l][p] * dec[l]*B[l][n]
__global__ __launch_bounds__(256)
void ssd_states_kernel(const f16* __restrict__ xbc, const float* __restrict__ dtb,
                       const float* __restrict__ Acum, f16* __restrict__ states) {
  __shared__ union {
    struct { f16 XdT[64][72]; f16 BT[128][72]; } s;  // 27 KB
    float Sl[64][132];                               // 33.8 KB
  } u;
  __shared__ float ac[64], dts[64];
  int bc = blockIdx.x >> 5, h = blockIdx.x & 31;
  int row0 = bc*64, t = threadIdx.x;
  if (t < 64) {
    ac[t]  = Acum[((size_t)bc*NH + h)*64 + t];
    dts[t] = dtb[(size_t)(row0 + t)*NH + h];
  }
  __syncthreads();
  float ac63 = ac[63];
#pragma unroll
  for (int i = 0; i < 2; ++i) {
    int idx = t + i*256; int l = idx >> 3, p8 = (idx & 7)*8;
    f16x8 v = *(const f16x8*)(xbc + (size_t)(row0 + l)*CONVD + h*HD + p8);
    float d = dts[l];
#pragma unroll
    for (int j = 0; j < 8; ++j) u.s.XdT[p8 + j][l] = (f16)((float)v[j]*d);
  }
#pragma unroll
  for (int i = 0; i < 4; ++i) {
    int idx = t + i*256; int l = idx >> 4, n8 = (idx & 15)*8;
    f16x8 v = *(const f16x8*)(xbc + (size_t)(row0 + l)*CONVD + BOFF + n8);
    float dl = __expf(ac63 - ac[l]);
#pragma unroll
    for (int j = 0; j < 8; ++j) u.s.BT[n8 + j][l] = (f16)((float)v[j]*dl);
  }
  __syncthreads();
  int wave = t >> 6, lane = t & 63;
  int lrow = lane & 15, kgrp = lane >> 4;
  f32x4 sacc[8] = {};
#pragma unroll
  for (int kk = 0; kk < 64; kk += 32) {
    f16x8 afs = *(const f16x8*)&u.s.XdT[wave*16 + lrow][kk + kgrp*8];
#pragma unroll
    for (int n = 0; n < 8; ++n) {
      f16x8 bf = *(const f16x8*)&u.s.BT[n*16 + lrow][kk + kgrp*8];
      sacc[n] = __builtin_amdgcn_mfma_f32_16x16x32_f16(afs, bf, sacc[n], 0, 0, 0);
    }
  }
  __syncthreads();
#pragma unroll
  for (int n = 0; n < 8; ++n)
#pragma unroll
    for (int r = 0; r < 4; ++r)
      u.Sl[wave*16 + kgrp*4 + r][n*16 + lrow] = sacc[n][r];
  __syncthreads();
  size_t sb = ((size_t)bc*NH + h)*8192;
#pragma unroll
  for (int i = 0; i < 4; ++i) {
    int idx = t + i*256; int p = idx >> 4, n8 = (idx & 15)*8;
    f16x8 o;
#pragma unroll
    for (int j = 0; j < 8; ++j) o[j] = (f16)u.Sl[p][n8 + j];
    *(f16x8*)(states + sb + (size_t)p*128 + n8) = o;
  }
}

// ---------------- inter-chunk scan (in place, fp16 storage, fp32 carry) ----------------
__global__ __launch_bounds__(256)
void scan_kernel(f16* __restrict__ states, const float* __restrict__ Acum) {
  int bid = blockIdx.x;
  int bh = bid >> 3, pgrp = bid & 7;
  int b = bh >> 5, h = bh & 31;
  int t = threadIdx.x;
  int p = pgrp*8 + (t >> 5), n4 = (t & 31) * 4;
  size_t off = (size_t)p*128 + n4;
  f32x4 carry = {0.f, 0.f, 0.f, 0.f};
  for (int c = 0; c < NC; ++c) {
    size_t base = ((size_t)(b*NC + c)*NH + h)*8192;
    f16x4 cv = *(f16x4*)(states + base + off);
    f16x4 st;
#pragma unroll
    for (int j = 0; j < 4; ++j) st[j] = (f16)carry[j];
    *(f16x4*)(states + base + off) = st;
    float tc = __expf(Acum[((size_t)(b*NC + c)*NH + h)*64 + 63]);
#pragma unroll
    for (int j = 0; j < 4; ++j) carry[j] = carry[j]*tc + (float)cv[j];
  }
}

// ------- per (b,c,h): Y_diag + Y_off + D-skip + SiLU(z) gating, Ybuf written ONCE -------
__global__ __launch_bounds__(256)
void yoff_kernel(const f16* __restrict__ xbc, const f16* __restrict__ zxh,
                 const f16* __restrict__ Gg, const f16* __restrict__ states,
                 const float* __restrict__ dtb, const float* __restrict__ Acum,
                 const float* __restrict__ Dp, f16* __restrict__ Ybuf) {
  __shared__ union {
    struct { f16 Gt[64][72]; f16 XdT[64][72]; } a;   // 18 KB (ydiag operands)
    struct { f16 Ch[64][136]; f16 Sin[64][136]; } b; // 34 KB (yoff operands)
    float Yl2[64][68];                               // 17 KB (yoff retile)
  } u;
  __shared__ float Yl[64][68];   // 17 KB, ydiag fp32, persists
  __shared__ float ac[64], dts[64], eac[64];
  int bc = blockIdx.x >> 5, h = blockIdx.x & 31;
  int row0 = bc*64, t = threadIdx.x;
  if (t < 64) {
    float a0 = Acum[((size_t)bc*NH + h)*64 + t];
    ac[t]  = a0;
    eac[t] = __expf(a0);
    dts[t] = dtb[(size_t)(row0 + t)*NH + h];
  }
  __syncthreads();
  // stage XdT[p][l] = x[l][p]*dt[l]
#pragma unroll
  for (int i = 0; i < 2; ++i) {
    int idx = t + i*256; int l = idx >> 3, p8 = (idx & 7)*8;
    f16x8 v = *(const f16x8*)(xbc + (size_t)(row0 + l)*CONVD + h*HD + p8);
    float d = dts[l];
#pragma unroll
    for (int j = 0; j < 8; ++j) u.a.XdT[p8 + j][l] = (f16)((float)v[j]*d);
  }
  // stage Gt[l][s] = (l>=s) ? G[l][s]*exp(ac[l]-ac[s]) : 0
#pragma unroll
  for (int i = 0; i < 2; ++i) {
    int idx = t + i*256; int l = idx >> 3, s8 = (idx & 7)*8;
    f16x8 g = *(const f16x8*)(Gg + (size_t)bc*4096 + l*64 + s8);
    float al = ac[l];
    f16x8 o;
#pragma unroll
    for (int j = 0; j < 8; ++j) {
      int s = s8 + j;
      o[j] = (l >= s) ? (f16)((float)g[j] * __expf(al - ac[s])) : (f16)0.f;
    }
    *(f16x8*)&u.a.Gt[l][s8] = o;
  }
  __syncthreads();
  int wave = t >> 6, lane = t & 63;
  int lrow = lane & 15, kgrp = lane >> 4;
  // ydiag MFMA: Y[l][p] = sum_s Gt[l][s] * Xd[s][p]
  f32x4 yacc[4] = {};
#pragma unroll
  for (int kk = 0; kk < 64; kk += 32) {
    f16x8 afy = *(const f16x8*)&u.a.Gt[wave*16 + lrow][kk + kgrp*8];
#pragma unroll
    for (int n = 0; n < 4; ++n) {
      f16x8 bf = *(const f16x8*)&u.a.XdT[n*16 + lrow][kk + kgrp*8];
      yacc[n] = __builtin_amdgcn_mfma_f32_16x16x32_f16(afy, bf, yacc[n], 0, 0, 0);
    }
  }
  __syncthreads();   // union.a reads done -> safe to reuse as union.b
  // retile ydiag into persistent fp32 Yl
#pragma unroll
  for (int n = 0; n < 4; ++n)
#pragma unroll
    for (int r = 0; r < 4; ++r)
      Yl[wave*16 + kgrp*4 + r][n*16 + lrow] = yacc[n][r];
  // stage Ch (C) and Sin (scanned states) into union.b
  size_t sb = ((size_t)bc*NH + h)*8192;
#pragma unroll
  for (int i = 0; i < 4; ++i) {
    int idx = t + i*256; int r = idx >> 4, c8 = (idx & 15)*8;
    *(f16x8*)&u.b.Ch[r][c8]  = *(const f16x8*)(xbc + (size_t)(row0 + r)*CONVD + COFF + c8);
    *(f16x8*)&u.b.Sin[r][c8] = *(const f16x8*)(states + sb + (size_t)r*128 + c8);
  }
  __syncthreads();
  // yoff MFMA: yoffraw[l][p] = sum_n C[l][n] * Sin[p][n]
  f32x4 acc[4] = {};
#pragma unroll
  for (int kk = 0; kk < 128; kk += 32) {
    f16x8 af = *(const f16x8*)&u.b.Ch[wave*16 + lrow][kk + kgrp*8];
#pragma unroll
    for (int n = 0; n < 4; ++n) {
      f16x8 bf = *(const f16x8*)&u.b.Sin[n*16 + lrow][kk + kgrp*8];
      acc[n] = __builtin_amdgcn_mfma_f32_16x16x32_f16(af, bf, acc[n], 0, 0, 0);
    }
  }
  __syncthreads();   // union.b reads done -> safe to reuse as Yl2
#pragma unroll
  for (int n = 0; n < 4; ++n)
#pragma unroll
    for (int r = 0; r < 4; ++r)
      u.Yl2[wave*16 + kgrp*4 + r][n*16 + lrow] = acc[n][r];
  __syncthreads();
  // epilogue: Y = (ydiag + eac*yoffraw + D*x) * silu(z); single Ybuf write
  float Dh = Dp[h];
#pragma unroll
  for (int i = 0; i < 2; ++i) {
    int idx = t + i*256; int l = idx >> 3, p8 = (idx & 7)*8;
    int row = row0 + l;
    f16x8 zh = *(const f16x8*)(zxh + (size_t)row*NZ + h*HD + p8);
    f16x8 xs = *(const f16x8*)(xbc + (size_t)row*CONVD + h*HD + p8);
    float e = eac[l];
    f16x8 o;
#pragma unroll
    for (int j = 0; j < 8; ++j) {
      float yv = Yl[l][p8 + j] + e*u.Yl2[l][p8 + j] + (float)xs[j]*Dh;
      o[j] = (f16)(yv * silu_f((float)zh[j]));
    }
    *(f16x8*)(Ybuf + (size_t)row*DIN + h*HD + p8) = o;
  }
}

// ------- RMS scale only: scale[row] = rsqrt(mean(Ybuf[row]^2)+eps) -------
// (norm_w folded into woutT; scale applied in gemm2 epilogue)
__global__ __launch_bounds__(256)
void rms_scale_kernel(const f16* __restrict__ yg, float* __restrict__ scale) {
  __shared__ float red[4];
  int row = blockIdx.x, t = threadIdx.x;
  f16x8 v = *(const f16x8*)(yg + (size_t)row*DIN + t*8);
  float ss = 0.f;
#pragma unroll
  for (int j = 0; j < 8; ++j) { float f = (float)v[j]; ss += f*f; }
#pragma unroll
  for (int off = 32; off > 0; off >>= 1) ss += __shfl_down(ss, off);
  if ((t & 63) == 0) red[t >> 6] = ss;
  __syncthreads();
  if (t == 0) {
    float tot = red[0] + red[1] + red[2] + red[3];
    scale[row] = rsqrtf(tot * (1.f/2048.f) + 1e-5f);
  }
}

// ---------------- host launcher ----------------
extern "C" void kernel_launch(void* const* d_in, const int* in_sizes, int n_in,
                              void* d_out, int out_size, void* d_ws, size_t ws_size,
                              hipStream_t stream) {
  const float* x       = (const float*)d_in[0];
  const float* W_in    = (const float*)d_in[1];
  const float* conv_w  = (const float*)d_in[2];
  const float* conv_b  = (const float*)d_in[3];
  const float* dt_bias = (const float*)d_in[4];
  const float* A_log   = (const float*)d_in[5];
  const float* Dp      = (const float*)d_in[6];
  const float* norm_w  = (const float*)d_in[7];
  const float* W_out   = (const float*)d_in[8];

  constexpr size_t WS_NEED = 213909504;
  if (ws_size < WS_NEED) return;  // clean fail instead of OOB crash

  char* w = (char*)d_ws;
  f16*   states = (f16*)(w + 0);
  f16*   winT   = (f16*)(w + 0);
  f16*   xh     = (f16*)(w + 33554432);
  f16*   woutT  = (f16*)(w + 33554432);
  f16*   zxh    = (f16*)(w + 67108864);
  f16*   xbcc   = (f16*)(w + 138412032);
  f16*   Ybuf   = (f16*)(w + 176160768);
  float* dtb    = (float*)(w + 209715200);
  float* Acum   = (float*)(w + 210763776);
  f16*   Gg     = (f16*)(w + 211812352);
  float* rscale = (float*)(w + 212860928);   // 32 KB

  tof16_kernel<<<4096, 256, 0, stream>>>(x, xh, MROWS*DM/8);
  transpose_f32_to_f16<<<dim3(NZ/32, DM/32), 256, 0, stream>>>(W_in, winT, DM, NZ, NPROJ, nullptr);
  gemm_t<256,128,4,2,true><<<(MROWS/256)*(NZ/128), 512, 0, stream>>>(xh, winT, zxh, MROWS, NZ, DM, NZ, nullptr);
  dt_kernel<<<MROWS/64, 256, 0, stream>>>(x, W_in, dt_bias, A_log, dtb, Acum);
  conv_kernel<<<MROWS*(CONVD/8)/256, 256, 0, stream>>>(zxh, conv_w, conv_b, xbcc);
  gbuf_kernel<<<BB*NC, 256, 0, stream>>>(xbcc, Gg);
  ssd_states_kernel<<<BB*NC*NH, 256, 0, stream>>>(xbcc, dtb, Acum, states);
  scan_kernel<<<BB*NH*8, 256, 0, stream>>>(states, Acum);
  yoff_kernel<<<BB*NC*NH, 256, 0, stream>>>(xbcc, zxh, Gg, states, dtb, Acum, Dp, Ybuf);
  transpose_f32_to_f16<<<dim3(DM/32, DIN/32), 256, 0, stream>>>(W_out, woutT, DIN, DM, DM, norm_w);
  rms_scale_kernel<<<MROWS, 256, 0, stream>>>(Ybuf, rscale);
  gemm_t<128,128,2,2,false><<<(MROWS/128)*(DM/128), 256, 0, stream>>>(Ybuf, woutT, d_out, MROWS, DM, DIN, DM, rscale);
}

// Round 17
// 392.620 us; speedup vs baseline: 1.1192x; 1.0850x over previous
//
#include <hip/hip_runtime.h>
#include <hip/hip_fp16.h>

typedef _Float16 f16;
typedef _Float16 f16x4 __attribute__((ext_vector_type(4)));
typedef _Float16 f16x8 __attribute__((ext_vector_type(8)));
typedef float f32x4 __attribute__((ext_vector_type(4)));

#define DEV __device__ __forceinline__

// ---- problem constants ----
constexpr int BB    = 2;
constexpr int LL    = 4096;
constexpr int DM    = 1024;
constexpr int DIN   = 2048;
constexpr int DST   = 128;
constexpr int NH    = 32;
constexpr int HD    = 64;
constexpr int NC    = 64;                  // chunks per batch
constexpr int MROWS = BB * LL;             // 8192
constexpr int NPROJ = 2*DIN + 2*DST + NH;  // 4384 (W_in row stride)
constexpr int NZ    = 2*DIN + 2*DST;       // 4352 (z + xBC, GEMM1 N)
constexpr int CONVD = DIN + 2*DST;         // 2304
constexpr int DT_OFF = 2*DIN + 2*DST;      // 4352
constexpr int BOFF  = DIN;                 // 2048 (within NZ / CONVD)
constexpr int COFF  = DIN + DST;           // 2176

DEV float silu_f(float v) { return v / (1.f + __expf(-v)); }

// wave-uniform LDS dest; HW writes lane i at dst + i*16B. Per-lane global src.
DEV void gload_lds16(const f16* gsrc, f16* lds_dst) {
  __builtin_amdgcn_global_load_lds(
      (const __attribute__((address_space(1))) void*)gsrc,
      (__attribute__((address_space(3))) void*)lds_dst, 16, 0, 0);
}

// ------------- transpose fp32[K rows][srcLd cols] -> fp16[N][K] -------------
// colScale (optional, size K): dst[n][k] = src[k][n] * colScale[k]
__global__ __launch_bounds__(256)
void transpose_f32_to_f16(const float* __restrict__ src, f16* __restrict__ dst,
                          int K, int N, int srcLd, const float* __restrict__ colScale) {
  __shared__ float tbuf[32][33];
  int n0 = blockIdx.x * 32, k0 = blockIdx.y * 32;
  int tx = threadIdx.x & 31, ty = threadIdx.x >> 5;  // 32 x 8
  for (int i = ty; i < 32; i += 8)
    tbuf[i][tx] = src[(size_t)(k0 + i)*srcLd + n0 + tx];
  __syncthreads();
  float cs = colScale ? colScale[k0 + tx] : 1.f;
  for (int i = ty; i < 32; i += 8)
    dst[(size_t)(n0 + i)*K + (k0 + tx)] = (f16)(tbuf[tx][i] * cs);
}

// ------- pipelined MFMA GEMM (R16 proven): C[M][ldc] = A[M][K] * Bt[N][K]^T -------
// 2-buffer LDS (48KB gemm1), boundary vmcnt(0)+barrier, stage(t+1) before
// compute(t). XCD-chunked swizzle (FETCH 110->90MB, R15). Optional rowScale.
// Plateau: ~109us / 29.5% MfmaUtil across all tested geometries -> closed.
template<int BM, int BN, int WM_, int WN_, bool C16>
__global__ __launch_bounds__(WM_*WN_*64, 2)
void gemm_t(const f16* __restrict__ A, const f16* __restrict__ Bt,
            void* __restrict__ Cp, int M, int N, int K, int ldc,
            const float* __restrict__ rowScale) {
  constexpr int THREADS = WM_*WN_*64;
  constexpr int WTM = BM/WM_, WTN = BN/WN_;
  constexpr int FM = WTM/16, FN = WTN/16;
  constexpr int LA = BM*4/THREADS, LB = BN*4/THREADS;  // 16B-chunk loads/thread
  __shared__ f16 As[2][BM*32];
  __shared__ f16 Bs[2][BN*32];
  const int nbn = N / BN;
  const int nwg = (int)gridDim.x;
  const int lb  = ((int)blockIdx.x & 7) * (nwg >> 3) + ((int)blockIdx.x >> 3);
  const int bm = lb / nbn, bn = lb % nbn;
  const int tid = threadIdx.x;
  const int wave = tid >> 6, lane = tid & 63;
  const int lrow = lane & 15, kgrp = lane >> 4;
  const int wm = wave / WN_, wn = wave % WN_;
  const int nt = K >> 5;
  const int bcol8 = (kgrp ^ ((lrow ^ (lrow >> 2)) & 3)) * 8;

  const f16* aptr[LA];
  const f16* bptr[LB];
#pragma unroll
  for (int i = 0; i < LA; ++i) {
    int s = tid + i*THREADS, row = s >> 2;
    int g = (s & 3) ^ ((row ^ (row >> 2)) & 3);
    aptr[i] = A + (size_t)(bm*BM + row)*K + g*8;
  }
#pragma unroll
  for (int i = 0; i < LB; ++i) {
    int s = tid + i*THREADS, row = s >> 2;
    int g = (s & 3) ^ ((row ^ (row >> 2)) & 3);
    bptr[i] = Bt + (size_t)(bn*BN + row)*K + g*8;
  }

  f32x4 acc[FM][FN] = {};

  auto STAGE = [&](int buf, int t) {
#pragma unroll
    for (int i = 0; i < LA; ++i)
      gload_lds16(aptr[i] + (size_t)t*32, As[buf] + (wave*64 + i*THREADS)*8);
#pragma unroll
    for (int i = 0; i < LB; ++i)
      gload_lds16(bptr[i] + (size_t)t*32, Bs[buf] + (wave*64 + i*THREADS)*8);
  };

  STAGE(0, 0);
  asm volatile("s_waitcnt vmcnt(0)" ::: "memory");
  __builtin_amdgcn_s_barrier();
  __builtin_amdgcn_sched_barrier(0);

  for (int t = 0; t < nt; ++t) {
    const int cur = t & 1;
    if (t + 1 < nt) STAGE(cur ^ 1, t + 1);
    const f16* Ab = As[cur];
    const f16* Bb = Bs[cur];
    f16x8 bf[FN];
#pragma unroll
    for (int n = 0; n < FN; ++n)
      bf[n] = *(const f16x8*)(Bb + (wn*WTN + n*16 + lrow)*32 + bcol8);
#pragma unroll
    for (int m = 0; m < FM; ++m) {
      f16x8 af = *(const f16x8*)(Ab + (wm*WTM + m*16 + lrow)*32 + bcol8);
#pragma unroll
      for (int n = 0; n < FN; ++n)
        acc[m][n] = __builtin_amdgcn_mfma_f32_16x16x32_f16(af, bf[n], acc[m][n], 0, 0, 0);
    }
    if (t + 1 < nt) {
      asm volatile("s_waitcnt vmcnt(0)" ::: "memory");
      __builtin_amdgcn_s_barrier();
      __builtin_amdgcn_sched_barrier(0);
    }
  }

  int crow0 = bm*BM + wm*WTM, ccol0 = bn*BN + wn*WTN;
#pragma unroll
  for (int m = 0; m < FM; ++m)
#pragma unroll
    for (int n = 0; n < FN; ++n) {
      int r0 = crow0 + m*16 + (lane >> 4)*4;
      int c0 = ccol0 + n*16 + (lane & 15);
#pragma unroll
      for (int r = 0; r < 4; ++r) {
        float v = acc[m][n][r];
        if (rowScale) v *= rowScale[r0 + r];
        if constexpr (C16) {
          f16* C = (f16*)Cp;
          C[(size_t)(r0 + r)*ldc + c0] = (f16)v;
        } else {
          float* C = (float*)Cp;
          C[(size_t)(r0 + r)*ldc + c0] = v;
        }
      }
    }
}

// ------- exact fp32 dt + fused per-chunk cumsum + fused x->f16 emit -------
// (block = one chunk of 64 rows; also writes xh rows while staging x)
__global__ __launch_bounds__(256)
void dt_kernel(const float* __restrict__ x, const float* __restrict__ Win,
               const float* __restrict__ dt_bias, const float* __restrict__ A_log,
               float* __restrict__ dt, float* __restrict__ Acum,
               f16* __restrict__ xh) {
  __shared__ float xs[64][132];
  __shared__ float ws[128][32];
  __shared__ float dts[64][32];
  int bc = blockIdx.x;
  int r0 = bc * 64;
  int t = threadIdx.x;
  int r = t >> 2, c0 = (t & 3) * 8;
  float acc[8] = {};
  for (int kt = 0; kt < 1024; kt += 128) {
    __syncthreads();
#pragma unroll
    for (int i = 0; i < 8; ++i) {
      int idx4 = t + i*256;
      int rr = idx4 >> 5, c4 = (idx4 & 31) * 4;
      f32x4 xv4 = *(const f32x4*)(x + (size_t)(r0 + rr)*1024 + kt + c4);
      *(f32x4*)&xs[rr][c4] = xv4;
      f16x4 xo = {(f16)xv4[0], (f16)xv4[1], (f16)xv4[2], (f16)xv4[3]};
      *(f16x4*)(xh + (size_t)(r0 + rr)*1024 + kt + c4) = xo;
    }
#pragma unroll
    for (int i = 0; i < 4; ++i) {
      int idx4 = t + i*256;
      int rr = idx4 >> 3, c4 = (idx4 & 7) * 4;
      *(f32x4*)&ws[rr][c4] = *(const f32x4*)(Win + (size_t)(kt + rr)*NPROJ + DT_OFF + c4);
    }
    __syncthreads();
#pragma unroll 8
    for (int k = 0; k < 128; ++k) {
      float xv = xs[r][k];
      f32x4 w0 = *(const f32x4*)&ws[k][c0];
      f32x4 w1 = *(const f32x4*)&ws[k][c0 + 4];
#pragma unroll
      for (int j = 0; j < 4; ++j) { acc[j] += xv * w0[j]; acc[4+j] += xv * w1[j]; }
    }
  }
#pragma unroll
  for (int j = 0; j < 8; ++j) {
    float v = acc[j] + dt_bias[c0 + j];
    float sp = (v > 20.f) ? v : log1pf(__expf(v));
    dt[(size_t)(r0 + r)*NH + c0 + j] = sp;
    dts[r][c0 + j] = sp;
  }
  __syncthreads();
  // fused acum: per-head inclusive cumsum over the chunk's 64 rows
  int wave = t >> 6, lane = t & 63;
  for (int hh = 0; hh < 8; ++hh) {
    int h = wave*8 + hh;
    float A = -__expf(A_log[h]);
    float v = A * dts[lane][h];
#pragma unroll
    for (int off = 1; off < 64; off <<= 1) {
      float u = __shfl_up(v, off);
      if (lane >= off) v += u;
    }
    Acum[((size_t)bc*NH + h)*64 + lane] = v;
  }
}

// ---------------- causal depthwise conv (k=4) + bias + silu -> fp16 ----------------
__global__ __launch_bounds__(256)
void conv_kernel(const f16* __restrict__ zxh, const float* __restrict__ cw,
                 const float* __restrict__ cb, f16* __restrict__ out) {
  int i = blockIdx.x * 256 + threadIdx.x;      // MROWS * 288
  int row = i / (CONVD/8);
  int c8  = (i - row*(CONVD/8)) * 8;
  int lb = row & (LL - 1);
  f32x4 a0 = *(const f32x4*)(cb + c8);
  f32x4 a1 = *(const f32x4*)(cb + c8 + 4);
#pragma unroll
  for (int j = 0; j < 4; ++j) {
    int lsrc = lb - 3 + j;
    if (lsrc >= 0) {
      f16x8 v = *(const f16x8*)(zxh + (size_t)(row - 3 + j)*NZ + BOFF + c8);
      f32x4 w0 = *(const f32x4*)(cw + j*CONVD + c8);
      f32x4 w1 = *(const f32x4*)(cw + j*CONVD + c8 + 4);
#pragma unroll
      for (int jj = 0; jj < 4; ++jj) {
        a0[jj] += (float)v[jj]   * w0[jj];
        a1[jj] += (float)v[4+jj] * w1[jj];
      }
    }
  }
  f16x8 o;
#pragma unroll
  for (int jj = 0; jj < 4; ++jj) {
    o[jj]   = (f16)silu_f(a0[jj]);
    o[4+jj] = (f16)silu_f(a1[jj]);
  }
  *(f16x8*)(out + (size_t)row*CONVD + c8) = o;
}

// ---------------- G[bc][l][s] = sum_n C[l,n] * B[s,n] (head-independent, f16 out) ----------------
__global__ __launch_bounds__(256)
void gbuf_kernel(const f16* __restrict__ xbc, f16* __restrict__ G) {
  __shared__ float Cs[64][128];
  __shared__ float Bsm[64][128];
  int bc = blockIdx.x;
  int row0 = bc * 64;
  int t = threadIdx.x;
#pragma unroll
  for (int i = 0; i < 4; ++i) {
    int idx = t + i*256;
    int r = idx >> 4, c8 = (idx & 15) * 8;
    f16x8 cv = *(const f16x8*)(xbc + (size_t)(row0 + r)*CONVD + COFF + c8);
    f16x8 bv = *(const f16x8*)(xbc + (size_t)(row0 + r)*CONVD + BOFF + c8);
    f32x4 c0v = {(float)cv[0], (float)cv[1], (float)cv[2], (float)cv[3]};
    f32x4 c1v = {(float)cv[4], (float)cv[5], (float)cv[6], (float)cv[7]};
    f32x4 b0v = {(float)bv[0], (float)bv[1], (float)bv[2], (float)bv[3]};
    f32x4 b1v = {(float)bv[4], (float)bv[5], (float)bv[6], (float)bv[7]};
    *(f32x4*)&Cs[r][c8]      = c0v;  *(f32x4*)&Cs[r][c8 + 4]  = c1v;
    *(f32x4*)&Bsm[r][c8]     = b0v;  *(f32x4*)&Bsm[r][c8 + 4] = b1v;
  }
  __syncthreads();
  int l0 = (t >> 4)*4, s0 = (t & 15)*4;
  float acc[4][4] = {};
  for (int n4 = 0; n4 < 128; n4 += 4) {
    f32x4 cv[4], bv[4];
#pragma unroll
    for (int i = 0; i < 4; ++i) cv[i] = *(const f32x4*)&Cs[l0 + i][n4];
#pragma unroll
    for (int j = 0; j < 4; ++j) bv[j] = *(const f32x4*)&Bsm[s0 + j][n4];
#pragma unroll
    for (int i = 0; i < 4; ++i)
#pragma unroll
      for (int j = 0; j < 4; ++j)
        acc[i][j] += cv[i][0]*bv[j][0] + cv[i][1]*bv[j][1] + cv[i][2]*bv[j][2] + cv[i][3]*bv[j][3];
  }
#pragma unroll
  for (int i = 0; i < 4; ++i) {
    f16x4 v = {(f16)acc[i][0], (f16)acc[i][1], (f16)acc[i][2], (f16)acc[i][3]};
    *(f16x4*)(G + ((size_t)bc*64 + l0 + i)*64 + s0) = v;
  }
}

// ------- per (bc, head-group of 4): chunk states (MFMA), raw B staged ONCE -------
// states[p][n] = sum_l (Xd[l][p]*dec[l]) * B[l][n]   (decay folded into XdT)
__global__ __launch_bounds__(256)
void ssd_states_kernel(const f16* __restrict__ xbc, const float* __restrict__ dtb,
                       const float* __restrict__ Acum, f16* __restrict__ states) {
  __shared__ f16 BT[128][72];    // raw B^T, shared across the head group (18.4KB)
  __shared__ f16 XdT[64][72];    // per-head (9.2KB)
  __shared__ float Sl[64][132];  // retile (33.8KB)  -> total ~62KB
  __shared__ float ac[64], dts[64];
  int bc = blockIdx.x >> 3, hg = blockIdx.x & 7;
  int row0 = bc*64, t = threadIdx.x;
  int wave = t >> 6, lane = t & 63;
  int lrow = lane & 15, kgrp = lane >> 4;
  // stage raw BT[n][l] = B[l][n]  (once per block)
#pragma unroll
  for (int i = 0; i < 4; ++i) {
    int idx = t + i*256; int l = idx >> 4, n8 = (idx & 15)*8;
    f16x8 v = *(const f16x8*)(xbc + (size_t)(row0 + l)*CONVD + BOFF + n8);
#pragma unroll
    for (int j = 0; j < 8; ++j) BT[n8 + j][l] = v[j];
  }
  for (int hh = 0; hh < 4; ++hh) {
    int h = hg*4 + hh;
    __syncthreads();  // prev head's Sl reads done; ac/dts safe to rewrite
    if (t < 64) {
      ac[t]  = Acum[((size_t)bc*NH + h)*64 + t];
      dts[t] = dtb[(size_t)(row0 + t)*NH + h];
    }
    __syncthreads();  // also covers BT staging on first iteration
    float ac63 = ac[63];
#pragma unroll
    for (int i = 0; i < 2; ++i) {
      int idx = t + i*256; int l = idx >> 3, p8 = (idx & 7)*8;
      f16x8 v = *(const f16x8*)(xbc + (size_t)(row0 + l)*CONVD + h*HD + p8);
      float d = dts[l] * __expf(ac63 - ac[l]);
#pragma unroll
      for (int j = 0; j < 8; ++j) XdT[p8 + j][l] = (f16)((float)v[j]*d);
    }
    __syncthreads();
    f32x4 sacc[8] = {};
#pragma unroll
    for (int kk = 0; kk < 64; kk += 32) {
      f16x8 afs = *(const f16x8*)&XdT[wave*16 + lrow][kk + kgrp*8];
#pragma unroll
      for (int n = 0; n < 8; ++n) {
        f16x8 bf = *(const f16x8*)&BT[n*16 + lrow][kk + kgrp*8];
        sacc[n] = __builtin_amdgcn_mfma_f32_16x16x32_f16(afs, bf, sacc[n], 0, 0, 0);
      }
    }
    __syncthreads();
#pragma unroll
    for (int n = 0; n < 8; ++n)
#pragma unroll
      for (int r = 0; r < 4; ++r)
        Sl[wave*16 + kgrp*4 + r][n*16 + lrow] = sacc[n][r];
    __syncthreads();
    size_t sb = ((size_t)bc*NH + h)*8192;
#pragma unroll
    for (int i = 0; i < 4; ++i) {
      int idx = t + i*256; int p = idx >> 4, n8 = (idx & 15)*8;
      f16x8 o;
#pragma unroll
      for (int j = 0; j < 8; ++j) o[j] = (f16)Sl[p][n8 + j];
      *(f16x8*)(states + sb + (size_t)p*128 + n8) = o;
    }
  }
}

// ---------------- inter-chunk scan (in place, fp16 storage, fp32 carry) ----------------
__global__ __launch_bounds__(256)
void scan_kernel(f16* __restrict__ states, const float* __restrict__ Acum) {
  int bid = blockIdx.x;
  int bh = bid >> 3, pgrp = bid & 7;
  int b = bh >> 5, h = bh & 31;
  int t = threadIdx.x;
  int p = pgrp*8 + (t >> 5), n4 = (t & 31) * 4;
  size_t off = (size_t)p*128 + n4;
  f32x4 carry = {0.f, 0.f, 0.f, 0.f};
  for (int c = 0; c < NC; ++c) {
    size_t base = ((size_t)(b*NC + c)*NH + h)*8192;
    f16x4 cv = *(f16x4*)(states + base + off);
    f16x4 st;
#pragma unroll
    for (int j = 0; j < 4; ++j) st[j] = (f16)carry[j];
    *(f16x4*)(states + base + off) = st;
    float tc = __expf(Acum[((size_t)(b*NC + c)*NH + h)*64 + 63]);
#pragma unroll
    for (int j = 0; j < 4; ++j) carry[j] = carry[j]*tc + (float)cv[j];
  }
}

// ------- per (b,c,h): Y_diag + Y_off + D-skip + SiLU(z) gating, Ybuf written ONCE -------
__global__ __launch_bounds__(256)
void yoff_kernel(const f16* __restrict__ xbc, const f16* __restrict__ zxh,
                 const f16* __restrict__ Gg, const f16* __restrict__ states,
                 const float* __restrict__ dtb, const float* __restrict__ Acum,
                 const float* __restrict__ Dp, f16* __restrict__ Ybuf) {
  __shared__ union {
    struct { f16 Gt[64][72]; f16 XdT[64][72]; } a;   // 18 KB (ydiag operands)
    struct { f16 Ch[64][136]; f16 Sin[64][136]; } b; // 34 KB (yoff operands)
    float Yl2[64][68];                               // 17 KB (yoff retile)
  } u;
  __shared__ float Yl[64][68];   // 17 KB, ydiag fp32, persists
  __shared__ float ac[64], dts[64], eac[64];
  int bc = blockIdx.x >> 5, h = blockIdx.x & 31;
  int row0 = bc*64, t = threadIdx.x;
  if (t < 64) {
    float a0 = Acum[((size_t)bc*NH + h)*64 + t];
    ac[t]  = a0;
    eac[t] = __expf(a0);
    dts[t] = dtb[(size_t)(row0 + t)*NH + h];
  }
  __syncthreads();
  // stage XdT[p][l] = x[l][p]*dt[l]
#pragma unroll
  for (int i = 0; i < 2; ++i) {
    int idx = t + i*256; int l = idx >> 3, p8 = (idx & 7)*8;
    f16x8 v = *(const f16x8*)(xbc + (size_t)(row0 + l)*CONVD + h*HD + p8);
    float d = dts[l];
#pragma unroll
    for (int j = 0; j < 8; ++j) u.a.XdT[p8 + j][l] = (f16)((float)v[j]*d);
  }
  // stage Gt[l][s] = (l>=s) ? G[l][s]*exp(ac[l]-ac[s]) : 0
#pragma unroll
  for (int i = 0; i < 2; ++i) {
    int idx = t + i*256; int l = idx >> 3, s8 = (idx & 7)*8;
    f16x8 g = *(const f16x8*)(Gg + (size_t)bc*4096 + l*64 + s8);
    float al = ac[l];
    f16x8 o;
#pragma unroll
    for (int j = 0; j < 8; ++j) {
      int s = s8 + j;
      o[j] = (l >= s) ? (f16)((float)g[j] * __expf(al - ac[s])) : (f16)0.f;
    }
    *(f16x8*)&u.a.Gt[l][s8] = o;
  }
  __syncthreads();
  int wave = t >> 6, lane = t & 63;
  int lrow = lane & 15, kgrp = lane >> 4;
  // ydiag MFMA: Y[l][p] = sum_s Gt[l][s] * Xd[s][p]
  f32x4 yacc[4] = {};
#pragma unroll
  for (int kk = 0; kk < 64; kk += 32) {
    f16x8 afy = *(const f16x8*)&u.a.Gt[wave*16 + lrow][kk + kgrp*8];
#pragma unroll
    for (int n = 0; n < 4; ++n) {
      f16x8 bf = *(const f16x8*)&u.a.XdT[n*16 + lrow][kk + kgrp*8];
      yacc[n] = __builtin_amdgcn_mfma_f32_16x16x32_f16(afy, bf, yacc[n], 0, 0, 0);
    }
  }
  __syncthreads();   // union.a reads done -> safe to reuse as union.b
  // retile ydiag into persistent fp32 Yl
#pragma unroll
  for (int n = 0; n < 4; ++n)
#pragma unroll
    for (int r = 0; r < 4; ++r)
      Yl[wave*16 + kgrp*4 + r][n*16 + lrow] = yacc[n][r];
  // stage Ch (C) and Sin (scanned states) into union.b
  size_t sb = ((size_t)bc*NH + h)*8192;
#pragma unroll
  for (int i = 0; i < 4; ++i) {
    int idx = t + i*256; int r = idx >> 4, c8 = (idx & 15)*8;
    *(f16x8*)&u.b.Ch[r][c8]  = *(const f16x8*)(xbc + (size_t)(row0 + r)*CONVD + COFF + c8);
    *(f16x8*)&u.b.Sin[r][c8] = *(const f16x8*)(states + sb + (size_t)r*128 + c8);
  }
  __syncthreads();
  // yoff MFMA: yoffraw[l][p] = sum_n C[l][n] * Sin[p][n]
  f32x4 acc[4] = {};
#pragma unroll
  for (int kk = 0; kk < 128; kk += 32) {
    f16x8 af = *(const f16x8*)&u.b.Ch[wave*16 + lrow][kk + kgrp*8];
#pragma unroll
    for (int n = 0; n < 4; ++n) {
      f16x8 bf = *(const f16x8*)&u.b.Sin[n*16 + lrow][kk + kgrp*8];
      acc[n] = __builtin_amdgcn_mfma_f32_16x16x32_f16(af, bf, acc[n], 0, 0, 0);
    }
  }
  __syncthreads();   // union.b reads done -> safe to reuse as Yl2
#pragma unroll
  for (int n = 0; n < 4; ++n)
#pragma unroll
    for (int r = 0; r < 4; ++r)
      u.Yl2[wave*16 + kgrp*4 + r][n*16 + lrow] = acc[n][r];
  __syncthreads();
  // epilogue: Y = (ydiag + eac*yoffraw + D*x) * silu(z); single Ybuf write
  float Dh = Dp[h];
#pragma unroll
  for (int i = 0; i < 2; ++i) {
    int idx = t + i*256; int l = idx >> 3, p8 = (idx & 7)*8;
    int row = row0 + l;
    f16x8 zh = *(const f16x8*)(zxh + (size_t)row*NZ + h*HD + p8);
    f16x8 xs = *(const f16x8*)(xbc + (size_t)row*CONVD + h*HD + p8);
    float e = eac[l];
    f16x8 o;
#pragma unroll
    for (int j = 0; j < 8; ++j) {
      float yv = Yl[l][p8 + j] + e*u.Yl2[l][p8 + j] + (float)xs[j]*Dh;
      o[j] = (f16)(yv * silu_f((float)zh[j]));
    }
    *(f16x8*)(Ybuf + (size_t)row*DIN + h*HD + p8) = o;
  }
}

// ------- RMS scale only: scale[row] = rsqrt(mean(Ybuf[row]^2)+eps) -------
// (norm_w folded into woutT; scale applied in gemm2 epilogue)
__global__ __launch_bounds__(256)
void rms_scale_kernel(const f16* __restrict__ yg, float* __restrict__ scale) {
  __shared__ float red[4];
  int row = blockIdx.x, t = threadIdx.x;
  f16x8 v = *(const f16x8*)(yg + (size_t)row*DIN + t*8);
  float ss = 0.f;
#pragma unroll
  for (int j = 0; j < 8; ++j) { float f = (float)v[j]; ss += f*f; }
#pragma unroll
  for (int off = 32; off > 0; off >>= 1) ss += __shfl_down(ss, off);
  if ((t & 63) == 0) red[t >> 6] = ss;
  __syncthreads();
  if (t == 0) {
    float tot = red[0] + red[1] + red[2] + red[3];
    scale[row] = rsqrtf(tot * (1.f/2048.f) + 1e-5f);
  }
}

// ---------------- host launcher ----------------
extern "C" void kernel_launch(void* const* d_in, const int* in_sizes, int n_in,
                              void* d_out, int out_size, void* d_ws, size_t ws_size,
                              hipStream_t stream) {
  const float* x       = (const float*)d_in[0];
  const float* W_in    = (const float*)d_in[1];
  const float* conv_w  = (const float*)d_in[2];
  const float* conv_b  = (const float*)d_in[3];
  const float* dt_bias = (const float*)d_in[4];
  const float* A_log   = (const float*)d_in[5];
  const float* Dp      = (const float*)d_in[6];
  const float* norm_w  = (const float*)d_in[7];
  const float* W_out   = (const float*)d_in[8];

  constexpr size_t WS_NEED = 213909504;
  if (ws_size < WS_NEED) return;  // clean fail instead of OOB crash

  char* w = (char*)d_ws;
  f16*   states = (f16*)(w + 0);
  f16*   winT   = (f16*)(w + 0);
  f16*   xh     = (f16*)(w + 33554432);
  f16*   woutT  = (f16*)(w + 33554432);
  f16*   zxh    = (f16*)(w + 67108864);
  f16*   xbcc   = (f16*)(w + 138412032);
  f16*   Ybuf   = (f16*)(w + 176160768);
  float* dtb    = (float*)(w + 209715200);
  float* Acum   = (float*)(w + 210763776);
  f16*   Gg     = (f16*)(w + 211812352);
  float* rscale = (float*)(w + 212860928);   // 32 KB

  dt_kernel<<<MROWS/64, 256, 0, stream>>>(x, W_in, dt_bias, A_log, dtb, Acum, xh);
  transpose_f32_to_f16<<<dim3(NZ/32, DM/32), 256, 0, stream>>>(W_in, winT, DM, NZ, NPROJ, nullptr);
  gemm_t<256,128,4,2,true><<<(MROWS/256)*(NZ/128), 512, 0, stream>>>(xh, winT, zxh, MROWS, NZ, DM, NZ, nullptr);
  conv_kernel<<<MROWS*(CONVD/8)/256, 256, 0, stream>>>(zxh, conv_w, conv_b, xbcc);
  gbuf_kernel<<<BB*NC, 256, 0, stream>>>(xbcc, Gg);
  ssd_states_kernel<<<BB*NC*(NH/4), 256, 0, stream>>>(xbcc, dtb, Acum, states);
  scan_kernel<<<BB*NH*8, 256, 0, stream>>>(states, Acum);
  yoff_kernel<<<BB*NC*NH, 256, 0, stream>>>(xbcc, zxh, Gg, states, dtb, Acum, Dp, Ybuf);
  transpose_f32_to_f16<<<dim3(DM/32, DIN/32), 256, 0, stream>>>(W_out, woutT, DIN, DM, DM, norm_w);
  rms_scale_kernel<<<MROWS, 256, 0, stream>>>(Ybuf, rscale);
  gemm_t<128,128,2,2,false><<<(MROWS/128)*(DM/128), 256, 0, stream>>>(Ybuf, woutT, d_out, MROWS, DM, DIN, DM, rscale);
}